// Round 1
// baseline (806.185 us; speedup 1.0000x reference)
//
#include <hip/hip_runtime.h>

using uint = unsigned int;
typedef short bf16x8 __attribute__((ext_vector_type(8)));
typedef float f32x4 __attribute__((ext_vector_type(4)));

static constexpr int Cc = 512;
static constexpr int Nn = 4096;              // H*W
static constexpr size_t NC = (size_t)Nn * Cc; // 2097152 elements

__device__ __forceinline__ unsigned short f2bf(float f) {
    unsigned int u = __builtin_bit_cast(unsigned int, f);
    u = (u + 0x7fff + ((u >> 16) & 1)) >> 16;
    return (unsigned short)u;
}

__device__ __forceinline__ void gll16(const void* g, void* l) {
    __builtin_amdgcn_global_load_lds(
        (const __attribute__((address_space(1))) void*)g,
        (__attribute__((address_space(3))) void*)l, 16, 0, 0);
}

// ---------------- fp32 -> bf16 weight convert ----------------
__global__ void cvt_kernel(const float* __restrict__ in, unsigned short* __restrict__ out, int n4) {
    int i = blockIdx.x * blockDim.x + threadIdx.x;
    if (i < n4) {
        float4 v = ((const float4*)in)[i];
        out[i * 4 + 0] = f2bf(v.x);
        out[i * 4 + 1] = f2bf(v.y);
        out[i * 4 + 2] = f2bf(v.z);
        out[i * 4 + 3] = f2bf(v.w);
    }
}

// ---------------- GroupNorm: x[B,C,N] fp32 -> h_t[B,N,C] bf16 ----------------
// one block per (b, g): slab = 16 channels x 4096, contiguous 64KB
__global__ void gn_kernel(const float* __restrict__ x, const float* __restrict__ gamma,
                          const float* __restrict__ beta, unsigned short* __restrict__ h_t) {
    int bg = blockIdx.x;
    int b = bg >> 5, g = bg & 31;
    const float* slab = x + ((size_t)(b * Cc + g * 16)) * Nn;
    const float4* s4 = (const float4*)slab;
    int t = threadIdx.x; // 256
    float s1 = 0.f, s2 = 0.f;
#pragma unroll 8
    for (int k = 0; k < 64; ++k) {
        float4 v = s4[k * 256 + t];
        s1 += v.x + v.y + v.z + v.w;
        s2 += v.x * v.x + v.y * v.y + v.z * v.z + v.w * v.w;
    }
#pragma unroll
    for (int o = 32; o > 0; o >>= 1) { s1 += __shfl_down(s1, o); s2 += __shfl_down(s2, o); }
    __shared__ float r1[4], r2[4];
    int wv_ = t >> 6, ln = t & 63;
    if (ln == 0) { r1[wv_] = s1; r2[wv_] = s2; }
    __syncthreads();
    if (t == 0) {
        float a1 = r1[0] + r1[1] + r1[2] + r1[3];
        float a2 = r2[0] + r2[1] + r2[2] + r2[3];
        float mean = a1 * (1.f / 65536.f);
        float var = a2 * (1.f / 65536.f) - mean * mean;
        r1[0] = mean;
        r2[0] = rsqrtf(var + 1e-6f);
    }
    __syncthreads();
    float mean = r1[0], rs = r2[0];
    unsigned short* hb = h_t + (size_t)b * NC;
#pragma unroll 4
    for (int k = 0; k < 64; ++k) {
        int idx4 = k * 256 + t;
        float4 v = s4[idx4];
        int idx = idx4 << 2;
        int c = idx >> 12;      // 0..15
        int i = idx & 4095;
        int cg = (g << 4) + c;
        float ga = gamma[cg], be = beta[cg];
        unsigned short* dst = hb + (size_t)i * Cc + cg;
        dst[0]        = f2bf((v.x - mean) * rs * ga + be);
        dst[Cc]       = f2bf((v.y - mean) * rs * ga + be);
        dst[2 * Cc]   = f2bf((v.z - mean) * rs * ga + be);
        dst[3 * Cc]   = f2bf((v.w - mean) * rs * ga + be);
    }
}

// ---------------- row softmax over S[4096,4096] fp32, write bf16 P in place (row stride 8192 bf16) ----
__global__ void softmax_kernel(float* __restrict__ S) {
    int row = blockIdx.x;
    float* srow = S + (size_t)row * Nn;
    const float4* s4 = (const float4*)srow;
    int t = threadIdx.x; // 256
    float4 v[4];
    float mx = -3.4e38f;
#pragma unroll
    for (int k = 0; k < 4; ++k) {
        v[k] = s4[k * 256 + t];
        mx = fmaxf(mx, fmaxf(fmaxf(v[k].x, v[k].y), fmaxf(v[k].z, v[k].w)));
    }
#pragma unroll
    for (int o = 32; o > 0; o >>= 1) mx = fmaxf(mx, __shfl_xor(mx, o));
    __shared__ float redm[4], reds[4];
    int wv_ = t >> 6, ln = t & 63;
    if (ln == 0) redm[wv_] = mx;
    __syncthreads();
    mx = fmaxf(fmaxf(redm[0], redm[1]), fmaxf(redm[2], redm[3]));
    float sum = 0.f;
#pragma unroll
    for (int k = 0; k < 4; ++k) {
        v[k].x = __expf(v[k].x - mx); sum += v[k].x;
        v[k].y = __expf(v[k].y - mx); sum += v[k].y;
        v[k].z = __expf(v[k].z - mx); sum += v[k].z;
        v[k].w = __expf(v[k].w - mx); sum += v[k].w;
    }
#pragma unroll
    for (int o = 32; o > 0; o >>= 1) sum += __shfl_xor(sum, o);
    if (ln == 0) reds[wv_] = sum;
    __syncthreads();
    sum = reds[0] + reds[1] + reds[2] + reds[3];
    float inv = 1.f / sum;
    uint2* prow = (uint2*)srow;  // bf16 row occupies first half of the fp32 row bytes
#pragma unroll
    for (int k = 0; k < 4; ++k) {
        uint a = (uint)f2bf(v[k].x * inv) | ((uint)f2bf(v[k].y * inv) << 16);
        uint b = (uint)f2bf(v[k].z * inv) | ((uint)f2bf(v[k].w * inv) << 16);
        prow[k * 256 + t] = make_uint2(a, b);
    }
}

// ---------------- GEMM: out[M,N] = (A[M,K] * Bt[N,K]^T + bias) * alpha (+res) ----------------
// bf16 A/Bt, fp32 accumulate. BIAS_MODE: 0 none, 1 bias[m], 2 bias[n].
template <int BIAS_MODE, int OUT_BF16, int HAS_RES>
__global__ __launch_bounds__(256) void gemm_bt(
    const unsigned short* __restrict__ A, int lda, size_t sA,
    const unsigned short* __restrict__ Bt, int ldb, size_t sB,
    void* __restrict__ outp, int ldc, size_t sC,
    const float* __restrict__ bias,
    const float* __restrict__ res, size_t sR,
    int K, float alpha) {
    __shared__ unsigned short lA[128 * 64];
    __shared__ unsigned short lB[128 * 64];
    int z = blockIdx.z;
    A += (size_t)z * sA;
    Bt += (size_t)z * sB;
    int m0 = blockIdx.y * 128, n0 = blockIdx.x * 128;
    int t = threadIdx.x;
    int lane = t & 63, wave = t >> 6;
    int wm = wave >> 1, wn = wave & 1;
    int lo = lane & 15, quad = lane >> 4;

    f32x4 acc[4][4];
#pragma unroll
    for (int a1 = 0; a1 < 4; ++a1)
#pragma unroll
        for (int a2 = 0; a2 < 4; ++a2) acc[a1][a2] = (f32x4){0.f, 0.f, 0.f, 0.f};

    for (int k0 = 0; k0 < K; k0 += 64) {
#pragma unroll
        for (int p = 0; p < 4; ++p) {
            int ci = p * 256 + t;
            int row = ci >> 3, c8 = ci & 7;
            gll16(A + (size_t)(m0 + row) * lda + k0 + c8 * 8, &lA[ci * 8]);
            gll16(Bt + (size_t)(n0 + row) * ldb + k0 + c8 * 8, &lB[ci * 8]);
        }
        __syncthreads();
#pragma unroll
        for (int ks = 0; ks < 64; ks += 32) {
            int kk = ks + quad * 8;
            bf16x8 af[4], bfr[4];
#pragma unroll
            for (int mt = 0; mt < 4; ++mt)
                af[mt] = *(const bf16x8*)&lA[(wm * 64 + mt * 16 + lo) * 64 + kk];
#pragma unroll
            for (int nt = 0; nt < 4; ++nt)
                bfr[nt] = *(const bf16x8*)&lB[(wn * 64 + nt * 16 + lo) * 64 + kk];
#pragma unroll
            for (int mt = 0; mt < 4; ++mt)
#pragma unroll
                for (int nt = 0; nt < 4; ++nt)
                    acc[mt][nt] = __builtin_amdgcn_mfma_f32_16x16x32_bf16(af[mt], bfr[nt], acc[mt][nt], 0, 0, 0);
        }
        __syncthreads();
    }

    size_t zc = (size_t)z * sC;
    float* outf = (float*)outp + zc;
    unsigned short* outb = (unsigned short*)outp + zc;
    const float* resz = HAS_RES ? res + (size_t)z * sR : nullptr;
#pragma unroll
    for (int mt = 0; mt < 4; ++mt) {
#pragma unroll
        for (int nt = 0; nt < 4; ++nt) {
            int row = m0 + wm * 64 + mt * 16 + quad * 4;
            int col = n0 + wn * 64 + nt * 16 + lo;
            float bn = (BIAS_MODE == 2) ? bias[col] : 0.f;
#pragma unroll
            for (int r = 0; r < 4; ++r) {
                float vv = acc[mt][nt][r];
                if (BIAS_MODE == 1) vv += bias[row + r];
                if (BIAS_MODE == 2) vv += bn;
                vv *= alpha;
                size_t off = (size_t)(row + r) * ldc + col;
                if (HAS_RES) vv += resz[off];
                if (OUT_BF16) outb[off] = f2bf(vv);
                else outf[off] = vv;
            }
        }
    }
}

extern "C" void kernel_launch(void* const* d_in, const int* in_sizes, int n_in,
                              void* d_out, int out_size, void* d_ws, size_t ws_size,
                              hipStream_t stream) {
    const float* x     = (const float*)d_in[0];
    const float* gamma = (const float*)d_in[1];
    const float* beta  = (const float*)d_in[2];
    const float* wq = (const float*)d_in[3];
    const float* bq = (const float*)d_in[4];
    const float* wk = (const float*)d_in[5];
    const float* bk = (const float*)d_in[6];
    const float* wv = (const float*)d_in[7];
    const float* bv = (const float*)d_in[8];
    const float* wo = (const float*)d_in[9];
    const float* bo = (const float*)d_in[10];

    char* ws = (char*)d_ws;
    unsigned short* h_t  = (unsigned short*)(ws);               // [B,N,C] bf16  16MB
    unsigned short* q_t  = (unsigned short*)(ws + 16777216);    // [B,N,C]
    unsigned short* k_t  = (unsigned short*)(ws + 33554432);    // [B,N,C]
    unsigned short* v_cn = (unsigned short*)(ws + 50331648);    // [B,C,N]
    unsigned short* o_t  = (unsigned short*)(ws + 67108864);    // [B,N,C]
    float* S             = (float*)(ws + 83886080);             // [4096,4096] fp32, reused per batch
    unsigned short* wqb  = (unsigned short*)(ws + 150994944);
    unsigned short* wkb  = (unsigned short*)(ws + 151519232);
    unsigned short* wvb  = (unsigned short*)(ws + 152043520);
    unsigned short* wob  = (unsigned short*)(ws + 152567808);

    const float SCALE = 0.044194173824159216f; // 512^-0.5

    // weight converts
    cvt_kernel<<<256, 256, 0, stream>>>(wq, wqb, 65536);
    cvt_kernel<<<256, 256, 0, stream>>>(wk, wkb, 65536);
    cvt_kernel<<<256, 256, 0, stream>>>(wv, wvb, 65536);
    cvt_kernel<<<256, 256, 0, stream>>>(wo, wob, 65536);

    // group norm -> h_t [B,N,C]
    gn_kernel<<<128, 256, 0, stream>>>(x, gamma, beta, h_t);

    // q_t = (h_t . Wq^T + bq) * scale   [N,C] bf16
    gemm_bt<2, 1, 0><<<dim3(4, 32, 4), 256, 0, stream>>>(
        h_t, Cc, NC, wqb, Cc, 0, q_t, Cc, NC, bq, nullptr, 0, Cc, SCALE);
    // k_t = h_t . Wk^T + bk
    gemm_bt<2, 1, 0><<<dim3(4, 32, 4), 256, 0, stream>>>(
        h_t, Cc, NC, wkb, Cc, 0, k_t, Cc, NC, bk, nullptr, 0, Cc, 1.f);
    // v_cn = Wv . h_t^T + bv   [C,N] bf16
    gemm_bt<1, 1, 0><<<dim3(32, 4, 4), 256, 0, stream>>>(
        wvb, Cc, 0, h_t, Cc, NC, v_cn, Nn, NC, bv, nullptr, 0, Cc, 1.f);

    for (int b = 0; b < 4; ++b) {
        // S = q_t . k_t^T    [4096,4096] fp32
        gemm_bt<0, 0, 0><<<dim3(32, 32, 1), 256, 0, stream>>>(
            q_t + (size_t)b * NC, Cc, 0, k_t + (size_t)b * NC, Cc, 0,
            S, Nn, 0, nullptr, nullptr, 0, Cc, 1.f);
        // softmax rows, write bf16 P in place (row stride 8192 bf16)
        softmax_kernel<<<4096, 256, 0, stream>>>(S);
        // o_t = P . v_cn^T   [4096,512] bf16
        gemm_bt<0, 1, 0><<<dim3(4, 32, 1), 256, 0, stream>>>(
            (unsigned short*)S, 8192, 0, v_cn + (size_t)b * NC, Nn, 0,
            o_t + (size_t)b * NC, Cc, 0, nullptr, nullptr, 0, Nn, 1.f);
    }

    // out = Wo . o_t^T + bo + x   [B,C,N] fp32 -> d_out
    gemm_bt<1, 0, 1><<<dim3(32, 4, 4), 256, 0, stream>>>(
        wob, Cc, 0, o_t, Cc, NC, d_out, Nn, NC, bo, x, NC, Cc, 1.f);
}

// Round 2
// 440.700 us; speedup vs baseline: 1.8293x; 1.8293x over previous
//
#include <hip/hip_runtime.h>

using uint = unsigned int;
typedef short bf16x8 __attribute__((ext_vector_type(8)));
typedef _Float16 f16x8 __attribute__((ext_vector_type(8)));
typedef float f32x4 __attribute__((ext_vector_type(4)));

static constexpr int Cc = 512;
static constexpr int Nn = 4096;               // H*W
static constexpr size_t NC = (size_t)Nn * Cc; // 2097152 elements
static constexpr size_t SN = (size_t)Nn * Nn; // 16777216 elements

__device__ __forceinline__ unsigned short f2bf(float f) {
    unsigned int u = __builtin_bit_cast(unsigned int, f);
    u = (u + 0x7fff + ((u >> 16) & 1)) >> 16;
    return (unsigned short)u;
}
__device__ __forceinline__ unsigned short f2h(float f) {
    _Float16 h = (_Float16)f;
    return __builtin_bit_cast(unsigned short, h);
}
__device__ __forceinline__ float h2f(unsigned short u) {
    return (float)__builtin_bit_cast(_Float16, u);
}

__device__ __forceinline__ void gll16(const void* g, void* l) {
    __builtin_amdgcn_global_load_lds(
        (const __attribute__((address_space(1))) void*)g,
        (__attribute__((address_space(3))) void*)l, 16, 0, 0);
}

// ---------------- fp32 -> bf16 weight convert ----------------
__global__ void cvt_kernel(const float* __restrict__ in, unsigned short* __restrict__ out, int n4) {
    int i = blockIdx.x * blockDim.x + threadIdx.x;
    if (i < n4) {
        float4 v = ((const float4*)in)[i];
        out[i * 4 + 0] = f2bf(v.x);
        out[i * 4 + 1] = f2bf(v.y);
        out[i * 4 + 2] = f2bf(v.z);
        out[i * 4 + 3] = f2bf(v.w);
    }
}

// ---------------- GN pass 1: stats per (b,g) ----------------
__global__ void gn_stats_kernel(const float* __restrict__ x, float* __restrict__ meanb,
                                float* __restrict__ rsb) {
    int bg = blockIdx.x; // 128 = B*32
    const float* slab = x + (size_t)bg * 16 * Nn;
    const float4* s4 = (const float4*)slab;
    int t = threadIdx.x; // 256
    float s1 = 0.f, s2 = 0.f;
#pragma unroll 8
    for (int k = 0; k < 64; ++k) {
        float4 v = s4[k * 256 + t];
        s1 += v.x + v.y + v.z + v.w;
        s2 += v.x * v.x + v.y * v.y + v.z * v.z + v.w * v.w;
    }
#pragma unroll
    for (int o = 32; o > 0; o >>= 1) { s1 += __shfl_down(s1, o); s2 += __shfl_down(s2, o); }
    __shared__ float r1[4], r2[4];
    int wv_ = t >> 6, ln = t & 63;
    if (ln == 0) { r1[wv_] = s1; r2[wv_] = s2; }
    __syncthreads();
    if (t == 0) {
        float a1 = r1[0] + r1[1] + r1[2] + r1[3];
        float a2 = r2[0] + r2[1] + r2[2] + r2[3];
        float mean = a1 * (1.f / 65536.f);
        float var = a2 * (1.f / 65536.f) - mean * mean;
        meanb[bg] = mean;
        rsb[bg] = rsqrtf(var + 1e-6f);
    }
}

// ---------------- GN pass 2: normalize + transpose via LDS tile ----------------
// x[B,C,N] fp32 -> h_t[B,N,C] bf16.  Tile: 64 channels x 64 tokens.
__global__ __launch_bounds__(256) void gn_norm_kernel(
    const float* __restrict__ x, const float* __restrict__ meanb, const float* __restrict__ rsb,
    const float* __restrict__ gamma, const float* __restrict__ beta,
    unsigned short* __restrict__ h_t) {
    __shared__ float tile[64][65];
    int n0 = blockIdx.x * 64, c0 = blockIdx.y * 64, b = blockIdx.z;
    int t = threadIdx.x;
    const float* xb = x + (size_t)b * Cc * Nn;
#pragma unroll
    for (int j = 0; j < 4; ++j) {
        int i = j * 256 + t;
        int c = i >> 4;       // 0..63
        int n4 = i & 15;      // float4 index within row
        int cg = c0 + c;
        float4 v = ((const float4*)(xb + (size_t)cg * Nn + n0))[n4];
        int g = cg >> 4;
        float mean = meanb[b * 32 + g], rs = rsb[b * 32 + g];
        float ga = gamma[cg] * rs;
        float be = beta[cg] - mean * ga;
        tile[n4 * 4 + 0][c] = v.x * ga + be;
        tile[n4 * 4 + 1][c] = v.y * ga + be;
        tile[n4 * 4 + 2][c] = v.z * ga + be;
        tile[n4 * 4 + 3][c] = v.w * ga + be;
    }
    __syncthreads();
    int n = t >> 2;                 // 0..63
    int cpart = (t & 3) * 16;       // 0,16,32,48
    unsigned short o[16];
#pragma unroll
    for (int q = 0; q < 16; ++q) o[q] = f2bf(tile[n][cpart + q]);
    unsigned short* dst = h_t + (size_t)b * NC + (size_t)(n0 + n) * Cc + c0 + cpart;
    ((uint4*)dst)[0] = ((uint4*)o)[0];
    ((uint4*)dst)[1] = ((uint4*)o)[1];
}

// ---------------- row softmax over fp16 S rows (in place) ----------------
__global__ void softmax_kernel(unsigned short* __restrict__ S) {
    size_t row = blockIdx.x;
    unsigned short* srow = S + row * Nn;
    int t = threadIdx.x; // 256; 4096 halfs = 512 uint4, 2 per thread
    uint4 u[2];
    u[0] = ((uint4*)srow)[t];
    u[1] = ((uint4*)srow)[t + 256];
    float f[16];
#pragma unroll
    for (int k = 0; k < 2; ++k) {
        uint* uu = (uint*)&u[k];
#pragma unroll
        for (int j = 0; j < 4; ++j) {
            f[k * 8 + j * 2 + 0] = h2f((unsigned short)(uu[j] & 0xffff));
            f[k * 8 + j * 2 + 1] = h2f((unsigned short)(uu[j] >> 16));
        }
    }
    float mx = -3.4e38f;
#pragma unroll
    for (int q = 0; q < 16; ++q) mx = fmaxf(mx, f[q]);
#pragma unroll
    for (int o = 32; o > 0; o >>= 1) mx = fmaxf(mx, __shfl_xor(mx, o));
    __shared__ float redm[4], reds[4];
    int wv_ = t >> 6, ln = t & 63;
    if (ln == 0) redm[wv_] = mx;
    __syncthreads();
    mx = fmaxf(fmaxf(redm[0], redm[1]), fmaxf(redm[2], redm[3]));
    float sum = 0.f;
#pragma unroll
    for (int q = 0; q < 16; ++q) { f[q] = __expf(f[q] - mx); sum += f[q]; }
#pragma unroll
    for (int o = 32; o > 0; o >>= 1) sum += __shfl_xor(sum, o);
    if (ln == 0) reds[wv_] = sum;
    __syncthreads();
    sum = reds[0] + reds[1] + reds[2] + reds[3];
    float inv = 1.f / sum;
#pragma unroll
    for (int k = 0; k < 2; ++k) {
        uint* uu = (uint*)&u[k];
#pragma unroll
        for (int j = 0; j < 4; ++j) {
            uu[j] = (uint)f2h(f[k * 8 + j * 2 + 0] * inv) |
                    ((uint)f2h(f[k * 8 + j * 2 + 1] * inv) << 16);
        }
    }
    ((uint4*)srow)[t] = u[0];
    ((uint4*)srow)[t + 256] = u[1];
}

// ---------------- GEMM: out[M,N] = (A[M,K] * Bt[N,K]^T + bias) * alpha (+res) ----------------
// 16-bit A/Bt, fp32 accumulate. DT: 0 bf16, 1 fp16. BIAS_MODE: 0 none, 1 bias[m], 2 bias[n].
// OUT_MODE: 0 fp32, 1 bf16, 2 fp16.
template <int DT, int BIAS_MODE, int OUT_MODE, int HAS_RES>
__global__ __launch_bounds__(256) void gemm_bt(
    const unsigned short* __restrict__ A, int lda, size_t sA,
    const unsigned short* __restrict__ Bt, int ldb, size_t sB,
    void* __restrict__ outp, int ldc, size_t sC,
    const float* __restrict__ bias,
    const float* __restrict__ res, size_t sR,
    int K, float alpha) {
    __shared__ unsigned short lA[128 * 64];
    __shared__ unsigned short lB[128 * 64];
    int z = blockIdx.z;
    A += (size_t)z * sA;
    Bt += (size_t)z * sB;
    int m0 = blockIdx.y * 128, n0 = blockIdx.x * 128;
    int t = threadIdx.x;
    int lane = t & 63, wave = t >> 6;
    int wm = wave >> 1, wn = wave & 1;
    int lo = lane & 15, quad = lane >> 4;

    f32x4 acc[4][4];
#pragma unroll
    for (int a1 = 0; a1 < 4; ++a1)
#pragma unroll
        for (int a2 = 0; a2 < 4; ++a2) acc[a1][a2] = (f32x4){0.f, 0.f, 0.f, 0.f};

    for (int k0 = 0; k0 < K; k0 += 64) {
#pragma unroll
        for (int p = 0; p < 4; ++p) {
            int ci = p * 256 + t;
            int row = ci >> 3, c8 = ci & 7;
            gll16(A + (size_t)(m0 + row) * lda + k0 + c8 * 8, &lA[ci * 8]);
            gll16(Bt + (size_t)(n0 + row) * ldb + k0 + c8 * 8, &lB[ci * 8]);
        }
        __syncthreads();
#pragma unroll
        for (int ks = 0; ks < 64; ks += 32) {
            int kk = ks + quad * 8;
            bf16x8 af[4], bfr[4];
#pragma unroll
            for (int mt = 0; mt < 4; ++mt)
                af[mt] = *(const bf16x8*)&lA[(wm * 64 + mt * 16 + lo) * 64 + kk];
#pragma unroll
            for (int nt = 0; nt < 4; ++nt)
                bfr[nt] = *(const bf16x8*)&lB[(wn * 64 + nt * 16 + lo) * 64 + kk];
#pragma unroll
            for (int mt = 0; mt < 4; ++mt)
#pragma unroll
                for (int nt = 0; nt < 4; ++nt) {
                    if (DT == 0)
                        acc[mt][nt] = __builtin_amdgcn_mfma_f32_16x16x32_bf16(af[mt], bfr[nt], acc[mt][nt], 0, 0, 0);
                    else
                        acc[mt][nt] = __builtin_amdgcn_mfma_f32_16x16x32_f16(
                            __builtin_bit_cast(f16x8, af[mt]), __builtin_bit_cast(f16x8, bfr[nt]),
                            acc[mt][nt], 0, 0, 0);
                }
        }
        __syncthreads();
    }

    size_t zc = (size_t)z * sC;
    float* outf = (float*)outp + zc;
    unsigned short* outb = (unsigned short*)outp + zc;
    const float* resz = HAS_RES ? res + (size_t)z * sR : nullptr;
#pragma unroll
    for (int mt = 0; mt < 4; ++mt) {
#pragma unroll
        for (int nt = 0; nt < 4; ++nt) {
            int row = m0 + wm * 64 + mt * 16 + quad * 4;
            int col = n0 + wn * 64 + nt * 16 + lo;
            float bn = (BIAS_MODE == 2) ? bias[col] : 0.f;
#pragma unroll
            for (int r = 0; r < 4; ++r) {
                float vv = acc[mt][nt][r];
                if (BIAS_MODE == 1) vv += bias[row + r];
                if (BIAS_MODE == 2) vv += bn;
                vv *= alpha;
                size_t off = (size_t)(row + r) * ldc + col;
                if (HAS_RES) vv += resz[off];
                if (OUT_MODE == 0) outf[off] = vv;
                else if (OUT_MODE == 1) outb[off] = f2bf(vv);
                else outb[off] = f2h(vv);
            }
        }
    }
}

extern "C" void kernel_launch(void* const* d_in, const int* in_sizes, int n_in,
                              void* d_out, int out_size, void* d_ws, size_t ws_size,
                              hipStream_t stream) {
    const float* x     = (const float*)d_in[0];
    const float* gamma = (const float*)d_in[1];
    const float* beta  = (const float*)d_in[2];
    const float* wq = (const float*)d_in[3];
    const float* bq = (const float*)d_in[4];
    const float* wk = (const float*)d_in[5];
    const float* bk = (const float*)d_in[6];
    const float* wv = (const float*)d_in[7];
    const float* bv = (const float*)d_in[8];
    const float* wo = (const float*)d_in[9];
    const float* bo = (const float*)d_in[10];

    char* ws = (char*)d_ws;
    unsigned short* h_t  = (unsigned short*)(ws);                 // [B,N,C] bf16 16MB
    unsigned short* q_t  = (unsigned short*)(ws + 16777216);      // [B,N,C] bf16
    unsigned short* k_t  = (unsigned short*)(ws + 33554432);      // [B,N,C] bf16
    unsigned short* v_h  = (unsigned short*)(ws + 50331648);      // [B,C,N] fp16
    unsigned short* o_t  = (unsigned short*)(ws + 67108864);      // [B,N,C] bf16
    unsigned short* S    = (unsigned short*)(ws + 83886080);      // [B,N,N] fp16 128MB
    unsigned short* wqb  = (unsigned short*)(ws + 218103808);
    unsigned short* wkb  = (unsigned short*)(ws + 218628096);
    unsigned short* wvb  = (unsigned short*)(ws + 219152384);
    unsigned short* wob  = (unsigned short*)(ws + 219676672);
    float* statm         = (float*)(ws + 220200960);              // [128]
    float* statr         = (float*)(ws + 220201984);              // [128]

    const float SCALE = 0.044194173824159216f; // 512^-0.5

    cvt_kernel<<<256, 256, 0, stream>>>(wq, wqb, 65536);
    cvt_kernel<<<256, 256, 0, stream>>>(wk, wkb, 65536);
    cvt_kernel<<<256, 256, 0, stream>>>(wv, wvb, 65536);
    cvt_kernel<<<256, 256, 0, stream>>>(wo, wob, 65536);

    gn_stats_kernel<<<128, 256, 0, stream>>>(x, statm, statr);
    gn_norm_kernel<<<dim3(64, 8, 4), 256, 0, stream>>>(x, statm, statr, gamma, beta, h_t);

    // q_t = (h . Wq^T + bq) * scale   bf16 [B,N,C]
    gemm_bt<0, 2, 1, 0><<<dim3(4, 32, 4), 256, 0, stream>>>(
        h_t, Cc, NC, wqb, Cc, 0, q_t, Cc, NC, bq, nullptr, 0, Cc, SCALE);
    // k_t = h . Wk^T + bk             bf16 [B,N,C]
    gemm_bt<0, 2, 1, 0><<<dim3(4, 32, 4), 256, 0, stream>>>(
        h_t, Cc, NC, wkb, Cc, 0, k_t, Cc, NC, bk, nullptr, 0, Cc, 1.f);
    // v_h = Wv . h^T + bv             fp16 [B,C,N]
    gemm_bt<0, 1, 2, 0><<<dim3(32, 4, 4), 256, 0, stream>>>(
        wvb, Cc, 0, h_t, Cc, NC, v_h, Nn, NC, bv, nullptr, 0, Cc, 1.f);

    // S = q . k^T  fp16 [B,N,N]
    gemm_bt<0, 0, 2, 0><<<dim3(32, 32, 4), 256, 0, stream>>>(
        q_t, Cc, NC, k_t, Cc, NC, S, Nn, SN, nullptr, nullptr, 0, Cc, 1.f);
    // softmax rows (in place, fp16)
    softmax_kernel<<<16384, 256, 0, stream>>>(S);
    // o_t = P . v^T   bf16 [B,N,C]   (f16 MFMA)
    gemm_bt<1, 0, 1, 0><<<dim3(4, 32, 4), 256, 0, stream>>>(
        S, Nn, SN, v_h, Nn, NC, o_t, Cc, NC, nullptr, nullptr, 0, Nn, 1.f);

    // out = Wo . o^T + bo + x   fp32 [B,C,N]
    gemm_bt<0, 1, 0, 1><<<dim3(32, 4, 4), 256, 0, stream>>>(
        wob, Cc, 0, o_t, Cc, NC, d_out, Nn, NC, bo, x, NC, Cc, 1.f);
}

// Round 3
// 430.274 us; speedup vs baseline: 1.8737x; 1.0242x over previous
//
#include <hip/hip_runtime.h>

using uint = unsigned int;
typedef short bf16x8 __attribute__((ext_vector_type(8)));
typedef _Float16 f16x8 __attribute__((ext_vector_type(8)));
typedef float f32x4 __attribute__((ext_vector_type(4)));

static constexpr int Cc = 512;
static constexpr int Nn = 4096;               // H*W
static constexpr size_t NC = (size_t)Nn * Cc; // 2097152 elements
static constexpr size_t SN = (size_t)Nn * Nn; // 16777216 elements

__device__ __forceinline__ unsigned short f2bf(float f) {
    unsigned int u = __builtin_bit_cast(unsigned int, f);
    u = (u + 0x7fff + ((u >> 16) & 1)) >> 16;
    return (unsigned short)u;
}
__device__ __forceinline__ unsigned short f2h(float f) {
    _Float16 h = (_Float16)f;
    return __builtin_bit_cast(unsigned short, h);
}
__device__ __forceinline__ float h2f(unsigned short u) {
    return (float)__builtin_bit_cast(_Float16, u);
}

__device__ __forceinline__ void gll16(const void* g, void* l) {
    __builtin_amdgcn_global_load_lds(
        (const __attribute__((address_space(1))) void*)g,
        (__attribute__((address_space(3))) void*)l, 16, 0, 0);
}

// ---------------- fp32 -> bf16 weight convert ----------------
__global__ void cvt_kernel(const float* __restrict__ in, unsigned short* __restrict__ out, int n4) {
    int i = blockIdx.x * blockDim.x + threadIdx.x;
    if (i < n4) {
        float4 v = ((const float4*)in)[i];
        out[i * 4 + 0] = f2bf(v.x);
        out[i * 4 + 1] = f2bf(v.y);
        out[i * 4 + 2] = f2bf(v.z);
        out[i * 4 + 3] = f2bf(v.w);
    }
}

// ---------------- GN pass 1: stats per (b,g) ----------------
__global__ void gn_stats_kernel(const float* __restrict__ x, float* __restrict__ meanb,
                                float* __restrict__ rsb) {
    int bg = blockIdx.x; // 128 = B*32
    const float* slab = x + (size_t)bg * 16 * Nn;
    const float4* s4 = (const float4*)slab;
    int t = threadIdx.x; // 256
    float s1 = 0.f, s2 = 0.f;
#pragma unroll 8
    for (int k = 0; k < 64; ++k) {
        float4 v = s4[k * 256 + t];
        s1 += v.x + v.y + v.z + v.w;
        s2 += v.x * v.x + v.y * v.y + v.z * v.z + v.w * v.w;
    }
#pragma unroll
    for (int o = 32; o > 0; o >>= 1) { s1 += __shfl_down(s1, o); s2 += __shfl_down(s2, o); }
    __shared__ float r1[4], r2[4];
    int wv_ = t >> 6, ln = t & 63;
    if (ln == 0) { r1[wv_] = s1; r2[wv_] = s2; }
    __syncthreads();
    if (t == 0) {
        float a1 = r1[0] + r1[1] + r1[2] + r1[3];
        float a2 = r2[0] + r2[1] + r2[2] + r2[3];
        float mean = a1 * (1.f / 65536.f);
        float var = a2 * (1.f / 65536.f) - mean * mean;
        meanb[bg] = mean;
        rsb[bg] = rsqrtf(var + 1e-6f);
    }
}

// ---------------- GN pass 2: normalize + transpose via LDS tile ----------------
__global__ __launch_bounds__(256) void gn_norm_kernel(
    const float* __restrict__ x, const float* __restrict__ meanb, const float* __restrict__ rsb,
    const float* __restrict__ gamma, const float* __restrict__ beta,
    unsigned short* __restrict__ h_t) {
    __shared__ float tile[64][65];
    int n0 = blockIdx.x * 64, c0 = blockIdx.y * 64, b = blockIdx.z;
    int t = threadIdx.x;
    const float* xb = x + (size_t)b * Cc * Nn;
#pragma unroll
    for (int j = 0; j < 4; ++j) {
        int i = j * 256 + t;
        int c = i >> 4;       // 0..63
        int n4 = i & 15;      // float4 index within row
        int cg = c0 + c;
        float4 v = ((const float4*)(xb + (size_t)cg * Nn + n0))[n4];
        int g = cg >> 4;
        float mean = meanb[b * 32 + g], rs = rsb[b * 32 + g];
        float ga = gamma[cg] * rs;
        float be = beta[cg] - mean * ga;
        tile[n4 * 4 + 0][c] = v.x * ga + be;
        tile[n4 * 4 + 1][c] = v.y * ga + be;
        tile[n4 * 4 + 2][c] = v.z * ga + be;
        tile[n4 * 4 + 3][c] = v.w * ga + be;
    }
    __syncthreads();
    int n = t >> 2;                 // 0..63
    int cpart = (t & 3) * 16;       // 0,16,32,48
    unsigned short o[16];
#pragma unroll
    for (int q = 0; q < 16; ++q) o[q] = f2bf(tile[n][cpart + q]);
    unsigned short* dst = h_t + (size_t)b * NC + (size_t)(n0 + n) * Cc + c0 + cpart;
    ((uint4*)dst)[0] = ((uint4*)o)[0];
    ((uint4*)dst)[1] = ((uint4*)o)[1];
}

// ---------------- row softmax over fp16 S rows (in place) ----------------
__global__ void softmax_kernel(unsigned short* __restrict__ S) {
    size_t row = blockIdx.x;
    unsigned short* srow = S + row * Nn;
    int t = threadIdx.x; // 256; 4096 halfs = 512 uint4, 2 per thread
    uint4 u[2];
    u[0] = ((uint4*)srow)[t];
    u[1] = ((uint4*)srow)[t + 256];
    float f[16];
#pragma unroll
    for (int k = 0; k < 2; ++k) {
        uint* uu = (uint*)&u[k];
#pragma unroll
        for (int j = 0; j < 4; ++j) {
            f[k * 8 + j * 2 + 0] = h2f((unsigned short)(uu[j] & 0xffff));
            f[k * 8 + j * 2 + 1] = h2f((unsigned short)(uu[j] >> 16));
        }
    }
    float mx = -3.4e38f;
#pragma unroll
    for (int q = 0; q < 16; ++q) mx = fmaxf(mx, f[q]);
#pragma unroll
    for (int o = 32; o > 0; o >>= 1) mx = fmaxf(mx, __shfl_xor(mx, o));
    __shared__ float redm[4], reds[4];
    int wv_ = t >> 6, ln = t & 63;
    if (ln == 0) redm[wv_] = mx;
    __syncthreads();
    mx = fmaxf(fmaxf(redm[0], redm[1]), fmaxf(redm[2], redm[3]));
    float sum = 0.f;
#pragma unroll
    for (int q = 0; q < 16; ++q) { f[q] = __expf(f[q] - mx); sum += f[q]; }
#pragma unroll
    for (int o = 32; o > 0; o >>= 1) sum += __shfl_xor(sum, o);
    if (ln == 0) reds[wv_] = sum;
    __syncthreads();
    sum = reds[0] + reds[1] + reds[2] + reds[3];
    float inv = 1.f / sum;
#pragma unroll
    for (int k = 0; k < 2; ++k) {
        uint* uu = (uint*)&u[k];
#pragma unroll
        for (int j = 0; j < 4; ++j) {
            uu[j] = (uint)f2h(f[k * 8 + j * 2 + 0] * inv) |
                    ((uint)f2h(f[k * 8 + j * 2 + 1] * inv) << 16);
        }
    }
    ((uint4*)srow)[t] = u[0];
    ((uint4*)srow)[t + 256] = u[1];
}

// ---------------- GEMM v2: out[M,N] = (A[M,K] * Bt[N,K]^T + bias) * alpha (+res) --------
// Block tile 256x128, 4 waves as 2x2, wave tile 128x64. BK=64.
// XOR-swizzled LDS (granule ^= row&7) -> conflict-free ds_read_b128 fragments.
// 16-bit A/Bt, fp32 acc. DT: 0 bf16, 1 fp16. BIAS_MODE: 0 none, 1 bias[m], 2 bias[n].
// OUT_MODE: 0 fp32, 1 bf16, 2 fp16.
template <int DT, int BIAS_MODE, int OUT_MODE, int HAS_RES>
__global__ __launch_bounds__(256, 2) void gemm_bt(
    const unsigned short* __restrict__ A, int lda, size_t sA,
    const unsigned short* __restrict__ Bt, int ldb, size_t sB,
    void* __restrict__ outp, int ldc, size_t sC,
    const float* __restrict__ bias,
    const float* __restrict__ res, size_t sR,
    int K, float alpha) {
    __shared__ unsigned short lA[256 * 64]; // 32 KB
    __shared__ unsigned short lB[128 * 64]; // 16 KB
    int z = blockIdx.z;
    A += (size_t)z * sA;
    Bt += (size_t)z * sB;
    int m0 = blockIdx.y * 256, n0 = blockIdx.x * 128;
    int t = threadIdx.x;
    int lane = t & 63, wave = t >> 6;
    int wm = wave >> 1, wn = wave & 1;       // wave tile: rows wm*128, cols wn*64
    int lo = lane & 15, quad = lane >> 4;

    f32x4 acc[8][4];
#pragma unroll
    for (int a1 = 0; a1 < 8; ++a1)
#pragma unroll
        for (int a2 = 0; a2 < 4; ++a2) acc[a1][a2] = (f32x4){0.f, 0.f, 0.f, 0.f};

    for (int k0 = 0; k0 < K; k0 += 64) {
#pragma unroll
        for (int p = 0; p < 8; ++p) {
            int ci = p * 256 + t;
            int row = ci >> 3;
            int gs = (ci ^ row) & 7;  // swizzled granule
            gll16(A + (size_t)(m0 + row) * lda + k0 + gs * 8, &lA[(size_t)ci * 8]);
        }
#pragma unroll
        for (int p = 0; p < 4; ++p) {
            int ci = p * 256 + t;
            int row = ci >> 3;
            int gs = (ci ^ row) & 7;
            gll16(Bt + (size_t)(n0 + row) * ldb + k0 + gs * 8, &lB[(size_t)ci * 8]);
        }
        __syncthreads();
#pragma unroll
        for (int ks = 0; ks < 2; ++ks) {
            int G = quad + ks * 4;  // granule index (8 halfs each)
            bf16x8 af[8], bfr[4];
#pragma unroll
            for (int mt = 0; mt < 8; ++mt) {
                int R = wm * 128 + mt * 16 + lo;
                af[mt] = *(const bf16x8*)&lA[R * 64 + (((G ^ R) & 7) << 3)];
            }
#pragma unroll
            for (int nt = 0; nt < 4; ++nt) {
                int R = wn * 64 + nt * 16 + lo;
                bfr[nt] = *(const bf16x8*)&lB[R * 64 + (((G ^ R) & 7) << 3)];
            }
#pragma unroll
            for (int mt = 0; mt < 8; ++mt)
#pragma unroll
                for (int nt = 0; nt < 4; ++nt) {
                    if (DT == 0)
                        acc[mt][nt] = __builtin_amdgcn_mfma_f32_16x16x32_bf16(af[mt], bfr[nt], acc[mt][nt], 0, 0, 0);
                    else
                        acc[mt][nt] = __builtin_amdgcn_mfma_f32_16x16x32_f16(
                            __builtin_bit_cast(f16x8, af[mt]), __builtin_bit_cast(f16x8, bfr[nt]),
                            acc[mt][nt], 0, 0, 0);
                }
        }
        __syncthreads();
    }

    size_t zc = (size_t)z * sC;
    float* outf = (float*)outp + zc;
    unsigned short* outb = (unsigned short*)outp + zc;
    const float* resz = HAS_RES ? res + (size_t)z * sR : nullptr;
#pragma unroll
    for (int mt = 0; mt < 8; ++mt) {
#pragma unroll
        for (int nt = 0; nt < 4; ++nt) {
            int row = m0 + wm * 128 + mt * 16 + quad * 4;
            int col = n0 + wn * 64 + nt * 16 + lo;
            float bn = (BIAS_MODE == 2) ? bias[col] : 0.f;
#pragma unroll
            for (int r = 0; r < 4; ++r) {
                float vv = acc[mt][nt][r];
                if (BIAS_MODE == 1) vv += bias[row + r];
                if (BIAS_MODE == 2) vv += bn;
                vv *= alpha;
                size_t off = (size_t)(row + r) * ldc + col;
                if (HAS_RES) vv += resz[off];
                if (OUT_MODE == 0) outf[off] = vv;
                else if (OUT_MODE == 1) outb[off] = f2bf(vv);
                else outb[off] = f2h(vv);
            }
        }
    }
}

extern "C" void kernel_launch(void* const* d_in, const int* in_sizes, int n_in,
                              void* d_out, int out_size, void* d_ws, size_t ws_size,
                              hipStream_t stream) {
    const float* x     = (const float*)d_in[0];
    const float* gamma = (const float*)d_in[1];
    const float* beta  = (const float*)d_in[2];
    const float* wq = (const float*)d_in[3];
    const float* bq = (const float*)d_in[4];
    const float* wk = (const float*)d_in[5];
    const float* bk = (const float*)d_in[6];
    const float* wv = (const float*)d_in[7];
    const float* bv = (const float*)d_in[8];
    const float* wo = (const float*)d_in[9];
    const float* bo = (const float*)d_in[10];

    char* ws = (char*)d_ws;
    unsigned short* h_t  = (unsigned short*)(ws);                 // [B,N,C] bf16 16MB
    unsigned short* q_t  = (unsigned short*)(ws + 16777216);      // [B,N,C] bf16
    unsigned short* k_t  = (unsigned short*)(ws + 33554432);      // [B,N,C] bf16
    unsigned short* v_h  = (unsigned short*)(ws + 50331648);      // [B,C,N] fp16
    unsigned short* o_t  = (unsigned short*)(ws + 67108864);      // [B,N,C] bf16
    unsigned short* S    = (unsigned short*)(ws + 83886080);      // [B,N,N] fp16 128MB
    unsigned short* wqb  = (unsigned short*)(ws + 218103808);
    unsigned short* wkb  = (unsigned short*)(ws + 218628096);
    unsigned short* wvb  = (unsigned short*)(ws + 219152384);
    unsigned short* wob  = (unsigned short*)(ws + 219676672);
    float* statm         = (float*)(ws + 220200960);              // [128]
    float* statr         = (float*)(ws + 220201984);              // [128]

    const float SCALE = 0.044194173824159216f; // 512^-0.5

    cvt_kernel<<<256, 256, 0, stream>>>(wq, wqb, 65536);
    cvt_kernel<<<256, 256, 0, stream>>>(wk, wkb, 65536);
    cvt_kernel<<<256, 256, 0, stream>>>(wv, wvb, 65536);
    cvt_kernel<<<256, 256, 0, stream>>>(wo, wob, 65536);

    gn_stats_kernel<<<128, 256, 0, stream>>>(x, statm, statr);
    gn_norm_kernel<<<dim3(64, 8, 4), 256, 0, stream>>>(x, statm, statr, gamma, beta, h_t);

    // q_t = (h . Wq^T + bq) * scale   bf16 [B,N,C]   M=4096 N=512
    gemm_bt<0, 2, 1, 0><<<dim3(4, 16, 4), 256, 0, stream>>>(
        h_t, Cc, NC, wqb, Cc, 0, q_t, Cc, NC, bq, nullptr, 0, Cc, SCALE);
    // k_t = h . Wk^T + bk             bf16 [B,N,C]
    gemm_bt<0, 2, 1, 0><<<dim3(4, 16, 4), 256, 0, stream>>>(
        h_t, Cc, NC, wkb, Cc, 0, k_t, Cc, NC, bk, nullptr, 0, Cc, 1.f);
    // v_h = Wv . h^T + bv             fp16 [B,C,N]   M=512 N=4096
    gemm_bt<0, 1, 2, 0><<<dim3(32, 2, 4), 256, 0, stream>>>(
        wvb, Cc, 0, h_t, Cc, NC, v_h, Nn, NC, bv, nullptr, 0, Cc, 1.f);

    // S = q . k^T  fp16 [B,N,N]   M=N=4096
    gemm_bt<0, 0, 2, 0><<<dim3(32, 16, 4), 256, 0, stream>>>(
        q_t, Cc, NC, k_t, Cc, NC, S, Nn, SN, nullptr, nullptr, 0, Cc, 1.f);
    // softmax rows (in place, fp16)
    softmax_kernel<<<16384, 256, 0, stream>>>(S);
    // o_t = P . v^T   bf16 [B,N,C]   M=4096 N=512 K=4096  (f16 MFMA)
    gemm_bt<1, 0, 1, 0><<<dim3(4, 16, 4), 256, 0, stream>>>(
        S, Nn, SN, v_h, Nn, NC, o_t, Cc, NC, nullptr, nullptr, 0, Nn, 1.f);

    // out = Wo . o^T + bo + x   fp32 [B,C,N]   M=512 N=4096
    gemm_bt<0, 1, 0, 1><<<dim3(32, 2, 4), 256, 0, stream>>>(
        wob, Cc, 0, o_t, Cc, NC, d_out, Nn, NC, bo, x, NC, Cc, 1.f);
}

// Round 4
// 377.828 us; speedup vs baseline: 2.1337x; 1.1388x over previous
//
#include <hip/hip_runtime.h>

using uint = unsigned int;
typedef short bf16x8 __attribute__((ext_vector_type(8)));
typedef _Float16 f16x8 __attribute__((ext_vector_type(8)));
typedef float f32x4 __attribute__((ext_vector_type(4)));

static constexpr int Cc = 512;
static constexpr int Nn = 4096;               // H*W
static constexpr size_t NC = (size_t)Nn * Cc; // 2097152 elements
static constexpr size_t SN = (size_t)Nn * Nn; // 16777216 elements

__device__ __forceinline__ unsigned short f2bf(float f) {
    unsigned int u = __builtin_bit_cast(unsigned int, f);
    u = (u + 0x7fff + ((u >> 16) & 1)) >> 16;
    return (unsigned short)u;
}
__device__ __forceinline__ unsigned short f2h(float f) {
    _Float16 h = (_Float16)f;
    return __builtin_bit_cast(unsigned short, h);
}
__device__ __forceinline__ float h2f(unsigned short u) {
    return (float)__builtin_bit_cast(_Float16, u);
}

__device__ __forceinline__ void gll16(const void* g, void* l) {
    __builtin_amdgcn_global_load_lds(
        (const __attribute__((address_space(1))) void*)g,
        (__attribute__((address_space(3))) void*)l, 16, 0, 0);
}

// ---------------- fp32 -> bf16 weight convert ----------------
__global__ void cvt_kernel(const float* __restrict__ in, unsigned short* __restrict__ out, int n4) {
    int i = blockIdx.x * blockDim.x + threadIdx.x;
    if (i < n4) {
        float4 v = ((const float4*)in)[i];
        out[i * 4 + 0] = f2bf(v.x);
        out[i * 4 + 1] = f2bf(v.y);
        out[i * 4 + 2] = f2bf(v.z);
        out[i * 4 + 3] = f2bf(v.w);
    }
}

// ---------------- zero the row-sum accumulator ----------------
__global__ void zero_kernel(float* __restrict__ p, int n4) {
    int i = blockIdx.x * blockDim.x + threadIdx.x;
    if (i < n4) ((float4*)p)[i] = make_float4(0.f, 0.f, 0.f, 0.f);
}

// ---------------- GN pass 1: stats per (b,g) ----------------
__global__ void gn_stats_kernel(const float* __restrict__ x, float* __restrict__ meanb,
                                float* __restrict__ rsb) {
    int bg = blockIdx.x; // 128 = B*32
    const float* slab = x + (size_t)bg * 16 * Nn;
    const float4* s4 = (const float4*)slab;
    int t = threadIdx.x; // 256
    float s1 = 0.f, s2 = 0.f;
#pragma unroll 8
    for (int k = 0; k < 64; ++k) {
        float4 v = s4[k * 256 + t];
        s1 += v.x + v.y + v.z + v.w;
        s2 += v.x * v.x + v.y * v.y + v.z * v.z + v.w * v.w;
    }
#pragma unroll
    for (int o = 32; o > 0; o >>= 1) { s1 += __shfl_down(s1, o); s2 += __shfl_down(s2, o); }
    __shared__ float r1[4], r2[4];
    int wv_ = t >> 6, ln = t & 63;
    if (ln == 0) { r1[wv_] = s1; r2[wv_] = s2; }
    __syncthreads();
    if (t == 0) {
        float a1 = r1[0] + r1[1] + r1[2] + r1[3];
        float a2 = r2[0] + r2[1] + r2[2] + r2[3];
        float mean = a1 * (1.f / 65536.f);
        float var = a2 * (1.f / 65536.f) - mean * mean;
        meanb[bg] = mean;
        rsb[bg] = rsqrtf(var + 1e-6f);
    }
}

// ---------------- GN pass 2: normalize + transpose via LDS tile ----------------
__global__ __launch_bounds__(256) void gn_norm_kernel(
    const float* __restrict__ x, const float* __restrict__ meanb, const float* __restrict__ rsb,
    const float* __restrict__ gamma, const float* __restrict__ beta,
    unsigned short* __restrict__ h_t) {
    __shared__ float tile[64][65];
    int n0 = blockIdx.x * 64, c0 = blockIdx.y * 64, b = blockIdx.z;
    int t = threadIdx.x;
    const float* xb = x + (size_t)b * Cc * Nn;
#pragma unroll
    for (int j = 0; j < 4; ++j) {
        int i = j * 256 + t;
        int c = i >> 4;       // 0..63
        int n4 = i & 15;      // float4 index within row
        int cg = c0 + c;
        float4 v = ((const float4*)(xb + (size_t)cg * Nn + n0))[n4];
        int g = cg >> 4;
        float mean = meanb[b * 32 + g], rs = rsb[b * 32 + g];
        float ga = gamma[cg] * rs;
        float be = beta[cg] - mean * ga;
        tile[n4 * 4 + 0][c] = v.x * ga + be;
        tile[n4 * 4 + 1][c] = v.y * ga + be;
        tile[n4 * 4 + 2][c] = v.z * ga + be;
        tile[n4 * 4 + 3][c] = v.w * ga + be;
    }
    __syncthreads();
    int n = t >> 2;                 // 0..63
    int cpart = (t & 3) * 16;       // 0,16,32,48
    unsigned short o[16];
#pragma unroll
    for (int q = 0; q < 16; ++q) o[q] = f2bf(tile[n][cpart + q]);
    unsigned short* dst = h_t + (size_t)b * NC + (size_t)(n0 + n) * Cc + c0 + cpart;
    ((uint4*)dst)[0] = ((uint4*)o)[0];
    ((uint4*)dst)[1] = ((uint4*)o)[1];
}

// ---------------- GEMM: out[M,N] = (A[M,K] * Bt[N,K]^T + bias) * alpha (+res) --------
// Block tile BM x 128, 4 waves as 2x2, wave tile (BM/2) x 64. BK=64.
// XOR-swizzled LDS -> conflict-free ds_read_b128 fragments.
// DT: 0 bf16, 1 fp16. BIAS_MODE: 0 none, 1 bias[m], 2 bias[n].
// OUT_MODE: 0 fp32, 1 bf16, 2 fp16.
// EPI: 0 plain; 1 = exp(v - 8) -> fp16 store + per-row atomic sum into lsum;
//      2 = divide by lsum[row] before store.
template <int BM, int DT, int BIAS_MODE, int OUT_MODE, int HAS_RES, int EPI>
__global__ __launch_bounds__(256, 2) void gemm_bt(
    const unsigned short* __restrict__ A, int lda, size_t sA,
    const unsigned short* __restrict__ Bt, int ldb, size_t sB,
    void* __restrict__ outp, int ldc, size_t sC,
    const float* __restrict__ bias,
    const float* __restrict__ res, size_t sR,
    float* __restrict__ lsum,
    int K, float alpha) {
    constexpr int MT = BM / 32;  // m-fragments per wave (4 or 8)
    __shared__ unsigned short lA[BM * 64];
    __shared__ unsigned short lB[128 * 64];
    int z = blockIdx.z;
    A += (size_t)z * sA;
    Bt += (size_t)z * sB;
    if (EPI) lsum += (size_t)z * Nn;
    int m0 = blockIdx.y * BM, n0 = blockIdx.x * 128;
    int t = threadIdx.x;
    int lane = t & 63, wave = t >> 6;
    int wm = wave >> 1, wn = wave & 1;
    int lo = lane & 15, quad = lane >> 4;

    f32x4 acc[MT][4];
#pragma unroll
    for (int a1 = 0; a1 < MT; ++a1)
#pragma unroll
        for (int a2 = 0; a2 < 4; ++a2) acc[a1][a2] = (f32x4){0.f, 0.f, 0.f, 0.f};

    for (int k0 = 0; k0 < K; k0 += 64) {
#pragma unroll
        for (int p = 0; p < MT; ++p) {
            int ci = p * 256 + t;
            int row = ci >> 3;
            int gs = (ci ^ row) & 7;  // swizzled granule
            gll16(A + (size_t)(m0 + row) * lda + k0 + gs * 8, &lA[(size_t)ci * 8]);
        }
#pragma unroll
        for (int p = 0; p < 4; ++p) {
            int ci = p * 256 + t;
            int row = ci >> 3;
            int gs = (ci ^ row) & 7;
            gll16(Bt + (size_t)(n0 + row) * ldb + k0 + gs * 8, &lB[(size_t)ci * 8]);
        }
        __syncthreads();
#pragma unroll
        for (int ks = 0; ks < 2; ++ks) {
            int G = quad + ks * 4;  // granule index (8 halfs each)
            bf16x8 af[MT], bfr[4];
#pragma unroll
            for (int mt = 0; mt < MT; ++mt) {
                int R = wm * (BM / 2) + mt * 16 + lo;
                af[mt] = *(const bf16x8*)&lA[R * 64 + (((G ^ R) & 7) << 3)];
            }
#pragma unroll
            for (int nt = 0; nt < 4; ++nt) {
                int R = wn * 64 + nt * 16 + lo;
                bfr[nt] = *(const bf16x8*)&lB[R * 64 + (((G ^ R) & 7) << 3)];
            }
#pragma unroll
            for (int mt = 0; mt < MT; ++mt)
#pragma unroll
                for (int nt = 0; nt < 4; ++nt) {
                    if (DT == 0)
                        acc[mt][nt] = __builtin_amdgcn_mfma_f32_16x16x32_bf16(af[mt], bfr[nt], acc[mt][nt], 0, 0, 0);
                    else
                        acc[mt][nt] = __builtin_amdgcn_mfma_f32_16x16x32_f16(
                            __builtin_bit_cast(f16x8, af[mt]), __builtin_bit_cast(f16x8, bfr[nt]),
                            acc[mt][nt], 0, 0, 0);
                }
        }
        __syncthreads();
    }

    size_t zc = (size_t)z * sC;
    float* outf = (float*)outp + zc;
    unsigned short* outb = (unsigned short*)outp + zc;
    const float* resz = HAS_RES ? res + (size_t)z * sR : nullptr;

    if (EPI == 1) {
        // exp epilogue: store exp(v*alpha - 8) as fp16, atomic per-row sums
#pragma unroll
        for (int mt = 0; mt < MT; ++mt) {
            int row = m0 + wm * (BM / 2) + mt * 16 + quad * 4;
            float rsum[4] = {0.f, 0.f, 0.f, 0.f};
#pragma unroll
            for (int nt = 0; nt < 4; ++nt) {
                int col = n0 + wn * 64 + nt * 16 + lo;
#pragma unroll
                for (int r = 0; r < 4; ++r) {
                    float e = __expf(acc[mt][nt][r] * alpha - 8.f);
                    outb[(size_t)(row + r) * ldc + col] = f2h(e);
                    rsum[r] += e;
                }
            }
#pragma unroll
            for (int o = 1; o < 16; o <<= 1) {
#pragma unroll
                for (int r = 0; r < 4; ++r) rsum[r] += __shfl_xor(rsum[r], o);
            }
            if (lo == 0) {
#pragma unroll
                for (int r = 0; r < 4; ++r) atomicAdd(&lsum[row + r], rsum[r]);
            }
        }
        return;
    }

#pragma unroll
    for (int mt = 0; mt < MT; ++mt) {
#pragma unroll
        for (int nt = 0; nt < 4; ++nt) {
            int row = m0 + wm * (BM / 2) + mt * 16 + quad * 4;
            int col = n0 + wn * 64 + nt * 16 + lo;
            float bn = (BIAS_MODE == 2) ? bias[col] : 0.f;
#pragma unroll
            for (int r = 0; r < 4; ++r) {
                float vv = acc[mt][nt][r];
                if (BIAS_MODE == 1) vv += bias[row + r];
                if (BIAS_MODE == 2) vv += bn;
                vv *= alpha;
                if (EPI == 2) vv /= lsum[row + r];
                size_t off = (size_t)(row + r) * ldc + col;
                if (HAS_RES) vv += resz[off];
                if (OUT_MODE == 0) outf[off] = vv;
                else if (OUT_MODE == 1) outb[off] = f2bf(vv);
                else outb[off] = f2h(vv);
            }
        }
    }
}

extern "C" void kernel_launch(void* const* d_in, const int* in_sizes, int n_in,
                              void* d_out, int out_size, void* d_ws, size_t ws_size,
                              hipStream_t stream) {
    const float* x     = (const float*)d_in[0];
    const float* gamma = (const float*)d_in[1];
    const float* beta  = (const float*)d_in[2];
    const float* wq = (const float*)d_in[3];
    const float* bq = (const float*)d_in[4];
    const float* wk = (const float*)d_in[5];
    const float* bk = (const float*)d_in[6];
    const float* wv = (const float*)d_in[7];
    const float* bv = (const float*)d_in[8];
    const float* wo = (const float*)d_in[9];
    const float* bo = (const float*)d_in[10];

    char* ws = (char*)d_ws;
    unsigned short* h_t  = (unsigned short*)(ws);                 // [B,N,C] bf16 16MB
    unsigned short* q_t  = (unsigned short*)(ws + 16777216);      // [B,N,C] bf16
    unsigned short* k_t  = (unsigned short*)(ws + 33554432);      // [B,N,C] bf16
    unsigned short* v_h  = (unsigned short*)(ws + 50331648);      // [B,C,N] fp16
    unsigned short* o_t  = (unsigned short*)(ws + 67108864);      // [B,N,C] bf16
    unsigned short* S    = (unsigned short*)(ws + 83886080);      // [B,N,N] fp16 128MB (expS)
    unsigned short* wqb  = (unsigned short*)(ws + 218103808);
    unsigned short* wkb  = (unsigned short*)(ws + 218628096);
    unsigned short* wvb  = (unsigned short*)(ws + 219152384);
    unsigned short* wob  = (unsigned short*)(ws + 219676672);
    float* statm         = (float*)(ws + 220200960);              // [128]
    float* statr         = (float*)(ws + 220201984);              // [128]
    float* lsum          = (float*)(ws + 220203008);              // [B*N] = 16384 floats

    const float SCALE = 0.044194173824159216f; // 512^-0.5

    cvt_kernel<<<256, 256, 0, stream>>>(wq, wqb, 65536);
    cvt_kernel<<<256, 256, 0, stream>>>(wk, wkb, 65536);
    cvt_kernel<<<256, 256, 0, stream>>>(wv, wvb, 65536);
    cvt_kernel<<<256, 256, 0, stream>>>(wo, wob, 65536);
    zero_kernel<<<16, 256, 0, stream>>>(lsum, 4096);

    gn_stats_kernel<<<128, 256, 0, stream>>>(x, statm, statr);
    gn_norm_kernel<<<dim3(64, 8, 4), 256, 0, stream>>>(x, statm, statr, gamma, beta, h_t);

    // q_t = (h . Wq^T + bq) * scale   bf16 [B,N,C]   M=4096 N=512
    gemm_bt<128, 0, 2, 1, 0, 0><<<dim3(4, 32, 4), 256, 0, stream>>>(
        h_t, Cc, NC, wqb, Cc, 0, q_t, Cc, NC, bq, nullptr, 0, nullptr, Cc, SCALE);
    // k_t = h . Wk^T + bk             bf16 [B,N,C]
    gemm_bt<128, 0, 2, 1, 0, 0><<<dim3(4, 32, 4), 256, 0, stream>>>(
        h_t, Cc, NC, wkb, Cc, 0, k_t, Cc, NC, bk, nullptr, 0, nullptr, Cc, 1.f);
    // v_h = Wv . h^T + bv             fp16 [B,C,N]   M=512 N=4096
    gemm_bt<128, 0, 1, 2, 0, 0><<<dim3(32, 4, 4), 256, 0, stream>>>(
        wvb, Cc, 0, h_t, Cc, NC, v_h, Nn, NC, bv, nullptr, 0, nullptr, Cc, 1.f);

    // expS = exp(q . k^T * scale - 8)  fp16 [B,N,N]; lsum = row sums
    gemm_bt<256, 0, 0, 2, 0, 1><<<dim3(32, 16, 4), 256, 0, stream>>>(
        q_t, Cc, NC, k_t, Cc, NC, S, Nn, SN, nullptr, nullptr, 0, lsum, Cc, 1.f);
    // o_t = (expS . v^T) / l   bf16 [B,N,C]   M=4096 N=512 K=4096  (f16 MFMA)
    gemm_bt<128, 1, 0, 1, 0, 2><<<dim3(4, 32, 4), 256, 0, stream>>>(
        S, Nn, SN, v_h, Nn, NC, o_t, Cc, NC, nullptr, nullptr, 0, lsum, Nn, 1.f);

    // out = Wo . o^T + bo + x   fp32 [B,C,N]   M=512 N=4096
    gemm_bt<128, 0, 1, 0, 1, 0><<<dim3(32, 4, 4), 256, 0, stream>>>(
        wob, Cc, 0, o_t, Cc, NC, d_out, Nn, NC, bo, x, NC, nullptr, Cc, 1.f);
}

// Round 5
// 336.876 us; speedup vs baseline: 2.3931x; 1.1216x over previous
//
#include <hip/hip_runtime.h>

using uint = unsigned int;
typedef short bf16x8 __attribute__((ext_vector_type(8)));
typedef _Float16 f16x8 __attribute__((ext_vector_type(8)));
typedef float f32x4 __attribute__((ext_vector_type(4)));
typedef long i64;

static constexpr int Cc = 512;
static constexpr int Nn = 4096;               // H*W
static constexpr size_t NC = (size_t)Nn * Cc; // 2097152 elements
static constexpr size_t SN = (size_t)Nn * Nn; // 16777216 elements

__device__ __forceinline__ unsigned short f2bf(float f) {
    unsigned int u = __builtin_bit_cast(unsigned int, f);
    u = (u + 0x7fff + ((u >> 16) & 1)) >> 16;
    return (unsigned short)u;
}
__device__ __forceinline__ unsigned short f2h(float f) {
    _Float16 h = (_Float16)f;
    return __builtin_bit_cast(unsigned short, h);
}

__device__ __forceinline__ void gll16(const void* g, void* l) {
    __builtin_amdgcn_global_load_lds(
        (const __attribute__((address_space(1))) void*)g,
        (__attribute__((address_space(3))) void*)l, 16, 0, 0);
}

// ---------------- fp32 -> bf16 weight convert ----------------
__global__ void cvt_kernel(const float* __restrict__ in, unsigned short* __restrict__ out, int n4) {
    int i = blockIdx.x * blockDim.x + threadIdx.x;
    if (i < n4) {
        float4 v = ((const float4*)in)[i];
        out[i * 4 + 0] = f2bf(v.x);
        out[i * 4 + 1] = f2bf(v.y);
        out[i * 4 + 2] = f2bf(v.z);
        out[i * 4 + 3] = f2bf(v.w);
    }
}

// ---------------- zero the row-sum accumulator ----------------
__global__ void zero_kernel(float* __restrict__ p, int n4) {
    int i = blockIdx.x * blockDim.x + threadIdx.x;
    if (i < n4) ((float4*)p)[i] = make_float4(0.f, 0.f, 0.f, 0.f);
}

// ---------------- GN pass 1: stats per (b,g) ----------------
__global__ void gn_stats_kernel(const float* __restrict__ x, float* __restrict__ meanb,
                                float* __restrict__ rsb) {
    int bg = blockIdx.x; // 128 = B*32
    const float* slab = x + (size_t)bg * 16 * Nn;
    const float4* s4 = (const float4*)slab;
    int t = threadIdx.x; // 256
    float s1 = 0.f, s2 = 0.f;
#pragma unroll 8
    for (int k = 0; k < 64; ++k) {
        float4 v = s4[k * 256 + t];
        s1 += v.x + v.y + v.z + v.w;
        s2 += v.x * v.x + v.y * v.y + v.z * v.z + v.w * v.w;
    }
#pragma unroll
    for (int o = 32; o > 0; o >>= 1) { s1 += __shfl_down(s1, o); s2 += __shfl_down(s2, o); }
    __shared__ float r1[4], r2[4];
    int wv_ = t >> 6, ln = t & 63;
    if (ln == 0) { r1[wv_] = s1; r2[wv_] = s2; }
    __syncthreads();
    if (t == 0) {
        float a1 = r1[0] + r1[1] + r1[2] + r1[3];
        float a2 = r2[0] + r2[1] + r2[2] + r2[3];
        float mean = a1 * (1.f / 65536.f);
        float var = a2 * (1.f / 65536.f) - mean * mean;
        meanb[bg] = mean;
        rsb[bg] = rsqrtf(var + 1e-6f);
    }
}

// ---------------- GN pass 2: normalize + transpose via LDS tile ----------------
__global__ __launch_bounds__(256) void gn_norm_kernel(
    const float* __restrict__ x, const float* __restrict__ meanb, const float* __restrict__ rsb,
    const float* __restrict__ gamma, const float* __restrict__ beta,
    unsigned short* __restrict__ h_t) {
    __shared__ float tile[64][65];
    int n0 = blockIdx.x * 64, c0 = blockIdx.y * 64, b = blockIdx.z;
    int t = threadIdx.x;
    const float* xb = x + (size_t)b * Cc * Nn;
#pragma unroll
    for (int j = 0; j < 4; ++j) {
        int i = j * 256 + t;
        int c = i >> 4;       // 0..63
        int n4 = i & 15;      // float4 index within row
        int cg = c0 + c;
        float4 v = ((const float4*)(xb + (size_t)cg * Nn + n0))[n4];
        int g = cg >> 4;
        float mean = meanb[b * 32 + g], rs = rsb[b * 32 + g];
        float ga = gamma[cg] * rs;
        float be = beta[cg] - mean * ga;
        tile[n4 * 4 + 0][c] = v.x * ga + be;
        tile[n4 * 4 + 1][c] = v.y * ga + be;
        tile[n4 * 4 + 2][c] = v.z * ga + be;
        tile[n4 * 4 + 3][c] = v.w * ga + be;
    }
    __syncthreads();
    int n = t >> 2;                 // 0..63
    int cpart = (t & 3) * 16;       // 0,16,32,48
    unsigned short o[16];
#pragma unroll
    for (int q = 0; q < 16; ++q) o[q] = f2bf(tile[n][cpart + q]);
    unsigned short* dst = h_t + (size_t)b * NC + (size_t)(n0 + n) * Cc + c0 + cpart;
    ((uint4*)dst)[0] = ((uint4*)o)[0];
    ((uint4*)dst)[1] = ((uint4*)o)[1];
}

// ---------------- GEMM: out[M,N] = (A[M,K] * Bt[N,K]^T + bias) * alpha (+res) --------
// Block tile BM x 128, 4 waves as 2x2, wave tile (BM/2) x 64. BK=64. bf16/f16 inputs.
// XOR-swizzled LDS -> conflict-free ds_read_b128 fragments.
// DT: 0 bf16, 1 fp16. BIAS_MODE: 0 none, 1 bias[m], 2 bias[n].
// OUT_MODE: 0 fp32, 1 bf16, 2 fp16, 3 fp8(e4m3).
// EPI: 0 plain; 1 = fp8 store of exp(v*alpha - 2) + per-row atomic sum of the
//      QUANTIZED values into lsum (consistent softmax normalization).
template <int BM, int DT, int BIAS_MODE, int OUT_MODE, int HAS_RES, int EPI>
__global__ __launch_bounds__(256, 2) void gemm_bt(
    const unsigned short* __restrict__ A, int lda, size_t sA,
    const unsigned short* __restrict__ Bt, int ldb, size_t sB,
    void* __restrict__ outp, int ldc, size_t sC,
    const float* __restrict__ bias,
    const float* __restrict__ res, size_t sR,
    float* __restrict__ lsum,
    int K, float alpha) {
    constexpr int MT = BM / 32;  // m-fragments per wave (4 or 8)
    __shared__ unsigned short lA[BM * 64];
    __shared__ unsigned short lB[128 * 64];
    int z = blockIdx.z;
    A += (size_t)z * sA;
    Bt += (size_t)z * sB;
    if (EPI) lsum += (size_t)z * Nn;
    int m0 = blockIdx.y * BM, n0 = blockIdx.x * 128;
    int t = threadIdx.x;
    int lane = t & 63, wave = t >> 6;
    int wm = wave >> 1, wn = wave & 1;
    int lo = lane & 15, quad = lane >> 4;

    f32x4 acc[MT][4];
#pragma unroll
    for (int a1 = 0; a1 < MT; ++a1)
#pragma unroll
        for (int a2 = 0; a2 < 4; ++a2) acc[a1][a2] = (f32x4){0.f, 0.f, 0.f, 0.f};

    for (int k0 = 0; k0 < K; k0 += 64) {
#pragma unroll
        for (int p = 0; p < MT; ++p) {
            int ci = p * 256 + t;
            int row = ci >> 3;
            int gs = (ci ^ row) & 7;  // swizzled granule
            gll16(A + (size_t)(m0 + row) * lda + k0 + gs * 8, &lA[(size_t)ci * 8]);
        }
#pragma unroll
        for (int p = 0; p < 4; ++p) {
            int ci = p * 256 + t;
            int row = ci >> 3;
            int gs = (ci ^ row) & 7;
            gll16(Bt + (size_t)(n0 + row) * ldb + k0 + gs * 8, &lB[(size_t)ci * 8]);
        }
        __syncthreads();
#pragma unroll
        for (int ks = 0; ks < 2; ++ks) {
            int G = quad + ks * 4;  // granule index (8 halfs each)
            bf16x8 af[MT], bfr[4];
#pragma unroll
            for (int mt = 0; mt < MT; ++mt) {
                int R = wm * (BM / 2) + mt * 16 + lo;
                af[mt] = *(const bf16x8*)&lA[R * 64 + (((G ^ R) & 7) << 3)];
            }
#pragma unroll
            for (int nt = 0; nt < 4; ++nt) {
                int R = wn * 64 + nt * 16 + lo;
                bfr[nt] = *(const bf16x8*)&lB[R * 64 + (((G ^ R) & 7) << 3)];
            }
#pragma unroll
            for (int mt = 0; mt < MT; ++mt)
#pragma unroll
                for (int nt = 0; nt < 4; ++nt) {
                    if (DT == 0)
                        acc[mt][nt] = __builtin_amdgcn_mfma_f32_16x16x32_bf16(af[mt], bfr[nt], acc[mt][nt], 0, 0, 0);
                    else
                        acc[mt][nt] = __builtin_amdgcn_mfma_f32_16x16x32_f16(
                            __builtin_bit_cast(f16x8, af[mt]), __builtin_bit_cast(f16x8, bfr[nt]),
                            acc[mt][nt], 0, 0, 0);
                }
        }
        __syncthreads();
    }

    size_t zc = (size_t)z * sC;
    float* outf = (float*)outp + zc;
    unsigned short* outb = (unsigned short*)outp + zc;
    unsigned char* outc = (unsigned char*)outp + zc;
    const float* resz = HAS_RES ? res + (size_t)z * sR : nullptr;

    if (EPI == 1) {
        // exp epilogue: store fp8(exp(v*alpha - 2)), atomic per-row sums of quantized values
#pragma unroll
        for (int mt = 0; mt < MT; ++mt) {
            int row = m0 + wm * (BM / 2) + mt * 16 + quad * 4;
            float rsum[4] = {0.f, 0.f, 0.f, 0.f};
#pragma unroll
            for (int nt = 0; nt < 4; ++nt) {
                int col = n0 + wn * 64 + nt * 16 + lo;
#pragma unroll
                for (int r = 0; r < 4; ++r) {
                    float e = __expf(acc[mt][nt][r] * alpha - 2.f);
                    e = fminf(e, 448.f);
                    int pk = __builtin_amdgcn_cvt_pk_fp8_f32(e, e, 0, false);
                    outc[(size_t)(row + r) * ldc + col] = (unsigned char)(pk & 0xff);
                    rsum[r] += __builtin_amdgcn_cvt_f32_fp8(pk, 0);
                }
            }
#pragma unroll
            for (int o = 1; o < 16; o <<= 1) {
#pragma unroll
                for (int r = 0; r < 4; ++r) rsum[r] += __shfl_xor(rsum[r], o);
            }
            if (lo == 0) {
#pragma unroll
                for (int r = 0; r < 4; ++r) atomicAdd(&lsum[row + r], rsum[r]);
            }
        }
        return;
    }

#pragma unroll
    for (int mt = 0; mt < MT; ++mt) {
#pragma unroll
        for (int nt = 0; nt < 4; ++nt) {
            int row = m0 + wm * (BM / 2) + mt * 16 + quad * 4;
            int col = n0 + wn * 64 + nt * 16 + lo;
            float bn = (BIAS_MODE == 2) ? bias[col] : 0.f;
#pragma unroll
            for (int r = 0; r < 4; ++r) {
                float vv = acc[mt][nt][r];
                if (BIAS_MODE == 1) vv += bias[row + r];
                if (BIAS_MODE == 2) vv += bn;
                vv *= alpha;
                size_t off = (size_t)(row + r) * ldc + col;
                if (HAS_RES) vv += resz[off];
                if (OUT_MODE == 0) outf[off] = vv;
                else if (OUT_MODE == 1) outb[off] = f2bf(vv);
                else if (OUT_MODE == 2) outb[off] = f2h(vv);
                else {
                    float e = fmaxf(fminf(vv, 448.f), -448.f);
                    int pk = __builtin_amdgcn_cvt_pk_fp8_f32(e, e, 0, false);
                    outc[off] = (unsigned char)(pk & 0xff);
                }
            }
        }
    }
}

// ---------------- PV: o_t[m,c] = (sum_j P[m,j] V[c,j]) / lsum[m], fp8 MFMA ----------------
// P fp8 [B,N,N] (row stride 4096 B), V fp8 [B,C,N]. Block tile 128x128, BK=128.
// 16B-granule XOR swizzle (g ^= row&7) -> 2-way banks on ds_read_b64 (free).
__global__ __launch_bounds__(256, 3) void pv_fp8(
    const unsigned char* __restrict__ S, const unsigned char* __restrict__ V,
    const float* __restrict__ lsum, unsigned short* __restrict__ o_t) {
    __shared__ unsigned char lA[128 * 128];
    __shared__ unsigned char lB[128 * 128];
    int z = blockIdx.z;
    S += (size_t)z * SN;
    V += (size_t)z * NC;
    lsum += (size_t)z * Nn;
    o_t += (size_t)z * NC;
    int m0 = blockIdx.y * 128, n0 = blockIdx.x * 128;
    int t = threadIdx.x;
    int lane = t & 63, wave = t >> 6;
    int wm = wave >> 1, wn = wave & 1;
    int lo = lane & 15, quad = lane >> 4;

    f32x4 acc[4][4];
#pragma unroll
    for (int a1 = 0; a1 < 4; ++a1)
#pragma unroll
        for (int a2 = 0; a2 < 4; ++a2) acc[a1][a2] = (f32x4){0.f, 0.f, 0.f, 0.f};

    for (int k0 = 0; k0 < Nn; k0 += 128) {
#pragma unroll
        for (int p = 0; p < 4; ++p) {
            int ci = p * 256 + t;
            int row = ci >> 3, g = ci & 7;
            int gs = g ^ (row & 7);
            gll16(S + (size_t)(m0 + row) * Nn + k0 + gs * 16, &lA[ci * 16]);
        }
#pragma unroll
        for (int p = 0; p < 4; ++p) {
            int ci = p * 256 + t;
            int row = ci >> 3, g = ci & 7;
            int gs = g ^ (row & 7);
            gll16(V + (size_t)(n0 + row) * Nn + k0 + gs * 16, &lB[ci * 16]);
        }
        __syncthreads();
#pragma unroll
        for (int ks = 0; ks < 4; ++ks) {
            int g16 = ks * 2 + (quad >> 1);  // 16B granule within 128B row
            int h8 = (quad & 1) * 8;
            i64 aq[4], bq[4];
#pragma unroll
            for (int mt = 0; mt < 4; ++mt) {
                int R = wm * 64 + mt * 16 + lo;
                aq[mt] = *(const i64*)&lA[R * 128 + ((g16 ^ (R & 7)) * 16) + h8];
            }
#pragma unroll
            for (int nt = 0; nt < 4; ++nt) {
                int R = wn * 64 + nt * 16 + lo;
                bq[nt] = *(const i64*)&lB[R * 128 + ((g16 ^ (R & 7)) * 16) + h8];
            }
#pragma unroll
            for (int mt = 0; mt < 4; ++mt)
#pragma unroll
                for (int nt = 0; nt < 4; ++nt)
                    acc[mt][nt] = __builtin_amdgcn_mfma_f32_16x16x32_fp8_fp8(aq[mt], bq[nt], acc[mt][nt], 0, 0, 0);
        }
        __syncthreads();
    }

#pragma unroll
    for (int mt = 0; mt < 4; ++mt)
#pragma unroll
        for (int nt = 0; nt < 4; ++nt) {
            int row = m0 + wm * 64 + mt * 16 + quad * 4;
            int col = n0 + wn * 64 + nt * 16 + lo;
#pragma unroll
            for (int r = 0; r < 4; ++r) {
                float vv = acc[mt][nt][r] / lsum[row + r];
                o_t[(size_t)(row + r) * Cc + col] = f2bf(vv);
            }
        }
}

extern "C" void kernel_launch(void* const* d_in, const int* in_sizes, int n_in,
                              void* d_out, int out_size, void* d_ws, size_t ws_size,
                              hipStream_t stream) {
    const float* x     = (const float*)d_in[0];
    const float* gamma = (const float*)d_in[1];
    const float* beta  = (const float*)d_in[2];
    const float* wq = (const float*)d_in[3];
    const float* bq = (const float*)d_in[4];
    const float* wk = (const float*)d_in[5];
    const float* bk = (const float*)d_in[6];
    const float* wv = (const float*)d_in[7];
    const float* bv = (const float*)d_in[8];
    const float* wo = (const float*)d_in[9];
    const float* bo = (const float*)d_in[10];

    char* ws = (char*)d_ws;
    unsigned short* h_t  = (unsigned short*)(ws);                 // [B,N,C] bf16 16MB
    unsigned short* q_t  = (unsigned short*)(ws + 16777216);      // [B,N,C] bf16
    unsigned short* k_t  = (unsigned short*)(ws + 33554432);      // [B,N,C] bf16
    unsigned char*  v_8  = (unsigned char*)(ws + 50331648);       // [B,C,N] fp8 8.4MB
    unsigned short* o_t  = (unsigned short*)(ws + 67108864);      // [B,N,C] bf16
    unsigned char*  S    = (unsigned char*)(ws + 83886080);       // [B,N,N] fp8 67MB
    unsigned short* wqb  = (unsigned short*)(ws + 218103808);
    unsigned short* wkb  = (unsigned short*)(ws + 218628096);
    unsigned short* wvb  = (unsigned short*)(ws + 219152384);
    unsigned short* wob  = (unsigned short*)(ws + 219676672);
    float* statm         = (float*)(ws + 220200960);              // [128]
    float* statr         = (float*)(ws + 220201984);              // [128]
    float* lsum          = (float*)(ws + 220203008);              // [B*N] = 16384 floats

    const float SCALE = 0.044194173824159216f; // 512^-0.5

    cvt_kernel<<<256, 256, 0, stream>>>(wq, wqb, 65536);
    cvt_kernel<<<256, 256, 0, stream>>>(wk, wkb, 65536);
    cvt_kernel<<<256, 256, 0, stream>>>(wv, wvb, 65536);
    cvt_kernel<<<256, 256, 0, stream>>>(wo, wob, 65536);
    zero_kernel<<<16, 256, 0, stream>>>(lsum, 4096);

    gn_stats_kernel<<<128, 256, 0, stream>>>(x, statm, statr);
    gn_norm_kernel<<<dim3(64, 8, 4), 256, 0, stream>>>(x, statm, statr, gamma, beta, h_t);

    // q_t = (h . Wq^T + bq) * scale   bf16 [B,N,C]   M=4096 N=512
    gemm_bt<128, 0, 2, 1, 0, 0><<<dim3(4, 32, 4), 256, 0, stream>>>(
        h_t, Cc, NC, wqb, Cc, 0, q_t, Cc, NC, bq, nullptr, 0, nullptr, Cc, SCALE);
    // k_t = h . Wk^T + bk             bf16 [B,N,C]
    gemm_bt<128, 0, 2, 1, 0, 0><<<dim3(4, 32, 4), 256, 0, stream>>>(
        h_t, Cc, NC, wkb, Cc, 0, k_t, Cc, NC, bk, nullptr, 0, nullptr, Cc, 1.f);
    // v_8 = fp8(Wv . h^T + bv)        fp8 [B,C,N]   M=512 N=4096
    gemm_bt<128, 0, 1, 3, 0, 0><<<dim3(32, 4, 4), 256, 0, stream>>>(
        wvb, Cc, 0, h_t, Cc, NC, v_8, Nn, NC, bv, nullptr, 0, nullptr, Cc, 1.f);

    // S = fp8(exp(q . k^T - 2))  [B,N,N]; lsum = quantized row sums
    gemm_bt<256, 0, 0, 3, 0, 1><<<dim3(32, 16, 4), 256, 0, stream>>>(
        q_t, Cc, NC, k_t, Cc, NC, S, Nn, SN, nullptr, nullptr, 0, lsum, Cc, 1.f);
    // o_t = (S . V^T) / lsum   bf16 [B,N,C]   fp8 MFMA
    pv_fp8<<<dim3(4, 32, 4), 256, 0, stream>>>(S, v_8, lsum, o_t);

    // out = Wo . o^T + bo + x   fp32 [B,C,N]   M=512 N=4096
    gemm_bt<128, 0, 1, 0, 1, 0><<<dim3(32, 4, 4), 256, 0, stream>>>(
        wob, Cc, 0, o_t, Cc, NC, d_out, Nn, NC, bo, x, NC, nullptr, Cc, 1.f);
}

// Round 6
// 325.001 us; speedup vs baseline: 2.4806x; 1.0365x over previous
//
#include <hip/hip_runtime.h>

using uint = unsigned int;
typedef short bf16x8 __attribute__((ext_vector_type(8)));
typedef _Float16 f16x8 __attribute__((ext_vector_type(8)));
typedef float f32x4 __attribute__((ext_vector_type(4)));
typedef long i64;

static constexpr int Cc = 512;
static constexpr int Nn = 4096;               // H*W
static constexpr size_t NC = (size_t)Nn * Cc; // 2097152 elements
static constexpr size_t SN = (size_t)Nn * Nn; // 16777216 elements

__device__ __forceinline__ unsigned short f2bf(float f) {
    unsigned int u = __builtin_bit_cast(unsigned int, f);
    u = (u + 0x7fff + ((u >> 16) & 1)) >> 16;
    return (unsigned short)u;
}
__device__ __forceinline__ unsigned short f2h(float f) {
    _Float16 h = (_Float16)f;
    return __builtin_bit_cast(unsigned short, h);
}

__device__ __forceinline__ void gll16(const void* g, void* l) {
    __builtin_amdgcn_global_load_lds(
        (const __attribute__((address_space(1))) void*)g,
        (__attribute__((address_space(3))) void*)l, 16, 0, 0);
}

// ---------------- fp32 -> bf16 weight convert ----------------
__global__ void cvt_kernel(const float* __restrict__ in, unsigned short* __restrict__ out, int n4) {
    int i = blockIdx.x * blockDim.x + threadIdx.x;
    if (i < n4) {
        float4 v = ((const float4*)in)[i];
        out[i * 4 + 0] = f2bf(v.x);
        out[i * 4 + 1] = f2bf(v.y);
        out[i * 4 + 2] = f2bf(v.z);
        out[i * 4 + 3] = f2bf(v.w);
    }
}

// ---------------- zero the row-sum accumulator ----------------
__global__ void zero_kernel(float* __restrict__ p, int n4) {
    int i = blockIdx.x * blockDim.x + threadIdx.x;
    if (i < n4) ((float4*)p)[i] = make_float4(0.f, 0.f, 0.f, 0.f);
}

// ---------------- GN pass 1: stats per (b,g) ----------------
__global__ void gn_stats_kernel(const float* __restrict__ x, float* __restrict__ meanb,
                                float* __restrict__ rsb) {
    int bg = blockIdx.x; // 128 = B*32
    const float* slab = x + (size_t)bg * 16 * Nn;
    const float4* s4 = (const float4*)slab;
    int t = threadIdx.x; // 256
    float s1 = 0.f, s2 = 0.f;
#pragma unroll 8
    for (int k = 0; k < 64; ++k) {
        float4 v = s4[k * 256 + t];
        s1 += v.x + v.y + v.z + v.w;
        s2 += v.x * v.x + v.y * v.y + v.z * v.z + v.w * v.w;
    }
#pragma unroll
    for (int o = 32; o > 0; o >>= 1) { s1 += __shfl_down(s1, o); s2 += __shfl_down(s2, o); }
    __shared__ float r1[4], r2[4];
    int wv_ = t >> 6, ln = t & 63;
    if (ln == 0) { r1[wv_] = s1; r2[wv_] = s2; }
    __syncthreads();
    if (t == 0) {
        float a1 = r1[0] + r1[1] + r1[2] + r1[3];
        float a2 = r2[0] + r2[1] + r2[2] + r2[3];
        float mean = a1 * (1.f / 65536.f);
        float var = a2 * (1.f / 65536.f) - mean * mean;
        meanb[bg] = mean;
        rsb[bg] = rsqrtf(var + 1e-6f);
    }
}

// ---------------- GN pass 2: normalize + transpose via LDS tile ----------------
__global__ __launch_bounds__(256) void gn_norm_kernel(
    const float* __restrict__ x, const float* __restrict__ meanb, const float* __restrict__ rsb,
    const float* __restrict__ gamma, const float* __restrict__ beta,
    unsigned short* __restrict__ h_t) {
    __shared__ float tile[64][65];
    int n0 = blockIdx.x * 64, c0 = blockIdx.y * 64, b = blockIdx.z;
    int t = threadIdx.x;
    const float* xb = x + (size_t)b * Cc * Nn;
#pragma unroll
    for (int j = 0; j < 4; ++j) {
        int i = j * 256 + t;
        int c = i >> 4;       // 0..63
        int n4 = i & 15;      // float4 index within row
        int cg = c0 + c;
        float4 v = ((const float4*)(xb + (size_t)cg * Nn + n0))[n4];
        int g = cg >> 4;
        float mean = meanb[b * 32 + g], rs = rsb[b * 32 + g];
        float ga = gamma[cg] * rs;
        float be = beta[cg] - mean * ga;
        tile[n4 * 4 + 0][c] = v.x * ga + be;
        tile[n4 * 4 + 1][c] = v.y * ga + be;
        tile[n4 * 4 + 2][c] = v.z * ga + be;
        tile[n4 * 4 + 3][c] = v.w * ga + be;
    }
    __syncthreads();
    int n = t >> 2;                 // 0..63
    int cpart = (t & 3) * 16;       // 0,16,32,48
    unsigned short o[16];
#pragma unroll
    for (int q = 0; q < 16; ++q) o[q] = f2bf(tile[n][cpart + q]);
    unsigned short* dst = h_t + (size_t)b * NC + (size_t)(n0 + n) * Cc + c0 + cpart;
    ((uint4*)dst)[0] = ((uint4*)o)[0];
    ((uint4*)dst)[1] = ((uint4*)o)[1];
}

// ---------------- bf16 GEMM: out[M,N] = (A[M,K] * Bt[N,K]^T + bias) * alpha (+res) --------
// Block tile BM x 128, 4 waves as 2x2, wave tile (BM/2) x 64. BK=64.
// DT: 0 bf16, 1 fp16. BIAS_MODE: 0 none, 1 bias[m], 2 bias[n].
// OUT_MODE: 0 fp32, 1 bf16, 2 fp16, 3 fp8(e4m3).
template <int BM, int DT, int BIAS_MODE, int OUT_MODE, int HAS_RES>
__global__ __launch_bounds__(256, 2) void gemm_bt(
    const unsigned short* __restrict__ A, int lda, size_t sA,
    const unsigned short* __restrict__ Bt, int ldb, size_t sB,
    void* __restrict__ outp, int ldc, size_t sC,
    const float* __restrict__ bias,
    const float* __restrict__ res, size_t sR,
    int K, float alpha) {
    constexpr int MT = BM / 32;  // m-fragments per wave (4 or 8)
    __shared__ unsigned short lA[BM * 64];
    __shared__ unsigned short lB[128 * 64];
    int z = blockIdx.z;
    A += (size_t)z * sA;
    Bt += (size_t)z * sB;
    int m0 = blockIdx.y * BM, n0 = blockIdx.x * 128;
    int t = threadIdx.x;
    int lane = t & 63, wave = t >> 6;
    int wm = wave >> 1, wn = wave & 1;
    int lo = lane & 15, quad = lane >> 4;

    f32x4 acc[MT][4];
#pragma unroll
    for (int a1 = 0; a1 < MT; ++a1)
#pragma unroll
        for (int a2 = 0; a2 < 4; ++a2) acc[a1][a2] = (f32x4){0.f, 0.f, 0.f, 0.f};

    for (int k0 = 0; k0 < K; k0 += 64) {
#pragma unroll
        for (int p = 0; p < MT; ++p) {
            int ci = p * 256 + t;
            int row = ci >> 3;
            int gs = (ci ^ row) & 7;  // swizzled granule
            gll16(A + (size_t)(m0 + row) * lda + k0 + gs * 8, &lA[(size_t)ci * 8]);
        }
#pragma unroll
        for (int p = 0; p < 4; ++p) {
            int ci = p * 256 + t;
            int row = ci >> 3;
            int gs = (ci ^ row) & 7;
            gll16(Bt + (size_t)(n0 + row) * ldb + k0 + gs * 8, &lB[(size_t)ci * 8]);
        }
        __syncthreads();
#pragma unroll
        for (int ks = 0; ks < 2; ++ks) {
            int G = quad + ks * 4;  // granule index (8 halfs each)
            bf16x8 af[MT], bfr[4];
#pragma unroll
            for (int mt = 0; mt < MT; ++mt) {
                int R = wm * (BM / 2) + mt * 16 + lo;
                af[mt] = *(const bf16x8*)&lA[R * 64 + (((G ^ R) & 7) << 3)];
            }
#pragma unroll
            for (int nt = 0; nt < 4; ++nt) {
                int R = wn * 64 + nt * 16 + lo;
                bfr[nt] = *(const bf16x8*)&lB[R * 64 + (((G ^ R) & 7) << 3)];
            }
#pragma unroll
            for (int mt = 0; mt < MT; ++mt)
#pragma unroll
                for (int nt = 0; nt < 4; ++nt) {
                    if (DT == 0)
                        acc[mt][nt] = __builtin_amdgcn_mfma_f32_16x16x32_bf16(af[mt], bfr[nt], acc[mt][nt], 0, 0, 0);
                    else
                        acc[mt][nt] = __builtin_amdgcn_mfma_f32_16x16x32_f16(
                            __builtin_bit_cast(f16x8, af[mt]), __builtin_bit_cast(f16x8, bfr[nt]),
                            acc[mt][nt], 0, 0, 0);
                }
        }
        __syncthreads();
    }

    size_t zc = (size_t)z * sC;
    float* outf = (float*)outp + zc;
    unsigned short* outb = (unsigned short*)outp + zc;
    unsigned char* outc = (unsigned char*)outp + zc;
    const float* resz = HAS_RES ? res + (size_t)z * sR : nullptr;

#pragma unroll
    for (int mt = 0; mt < MT; ++mt) {
#pragma unroll
        for (int nt = 0; nt < 4; ++nt) {
            int row = m0 + wm * (BM / 2) + mt * 16 + quad * 4;
            int col = n0 + wn * 64 + nt * 16 + lo;
            float bn = (BIAS_MODE == 2) ? bias[col] : 0.f;
#pragma unroll
            for (int r = 0; r < 4; ++r) {
                float vv = acc[mt][nt][r];
                if (BIAS_MODE == 1) vv += bias[row + r];
                if (BIAS_MODE == 2) vv += bn;
                vv *= alpha;
                size_t off = (size_t)(row + r) * ldc + col;
                if (HAS_RES) vv += resz[off];
                if (OUT_MODE == 0) outf[off] = vv;
                else if (OUT_MODE == 1) outb[off] = f2bf(vv);
                else if (OUT_MODE == 2) outb[off] = f2h(vv);
                else {
                    float e = fmaxf(fminf(vv, 448.f), -448.f);
                    int pk = __builtin_amdgcn_cvt_pk_fp8_f32(e, e, 0, false);
                    outc[off] = (unsigned char)(pk & 0xff);
                }
            }
        }
    }
}

// ---------------- QK: S = fp8(exp((Q.K^T)*alpha - 2)), lsum += quantized row sums ----
// Q,K fp8 [B,N,C]. Block tile 256x128, waves 2x2 (wave 128x64), BK=128.
// Same 16B-granule XOR swizzle as pv_fp8 (proven conflict-free).
__global__ __launch_bounds__(256, 2) void qk_fp8(
    const unsigned char* __restrict__ Q, const unsigned char* __restrict__ Kt,
    unsigned char* __restrict__ S, float* __restrict__ lsum, float alpha) {
    __shared__ unsigned char lA[256 * 128]; // 32 KB
    __shared__ unsigned char lB[128 * 128]; // 16 KB
    int z = blockIdx.z;
    Q += (size_t)z * NC;
    Kt += (size_t)z * NC;
    S += (size_t)z * SN;
    lsum += (size_t)z * Nn;
    int m0 = blockIdx.y * 256, n0 = blockIdx.x * 128;
    int t = threadIdx.x;
    int lane = t & 63, wave = t >> 6;
    int wm = wave >> 1, wn = wave & 1;
    int lo = lane & 15, quad = lane >> 4;

    f32x4 acc[8][4];
#pragma unroll
    for (int a1 = 0; a1 < 8; ++a1)
#pragma unroll
        for (int a2 = 0; a2 < 4; ++a2) acc[a1][a2] = (f32x4){0.f, 0.f, 0.f, 0.f};

    for (int k0 = 0; k0 < Cc; k0 += 128) {
#pragma unroll
        for (int p = 0; p < 8; ++p) {
            int ci = p * 256 + t;
            int row = ci >> 3, g = ci & 7;
            int gs = g ^ (row & 7);
            gll16(Q + (size_t)(m0 + row) * Cc + k0 + gs * 16, &lA[ci * 16]);
        }
#pragma unroll
        for (int p = 0; p < 4; ++p) {
            int ci = p * 256 + t;
            int row = ci >> 3, g = ci & 7;
            int gs = g ^ (row & 7);
            gll16(Kt + (size_t)(n0 + row) * Cc + k0 + gs * 16, &lB[ci * 16]);
        }
        __syncthreads();
#pragma unroll
        for (int ks = 0; ks < 4; ++ks) {
            int g16 = ks * 2 + (quad >> 1);  // 16B granule within 128B row
            int h8 = (quad & 1) * 8;
            i64 aq[8], bq[4];
#pragma unroll
            for (int mt = 0; mt < 8; ++mt) {
                int R = wm * 128 + mt * 16 + lo;
                aq[mt] = *(const i64*)&lA[R * 128 + ((g16 ^ (R & 7)) * 16) + h8];
            }
#pragma unroll
            for (int nt = 0; nt < 4; ++nt) {
                int R = wn * 64 + nt * 16 + lo;
                bq[nt] = *(const i64*)&lB[R * 128 + ((g16 ^ (R & 7)) * 16) + h8];
            }
#pragma unroll
            for (int mt = 0; mt < 8; ++mt)
#pragma unroll
                for (int nt = 0; nt < 4; ++nt)
                    acc[mt][nt] = __builtin_amdgcn_mfma_f32_16x16x32_fp8_fp8(aq[mt], bq[nt], acc[mt][nt], 0, 0, 0);
        }
        __syncthreads();
    }

#pragma unroll
    for (int mt = 0; mt < 8; ++mt) {
        int row = m0 + wm * 128 + mt * 16 + quad * 4;
        float rsum[4] = {0.f, 0.f, 0.f, 0.f};
#pragma unroll
        for (int nt = 0; nt < 4; ++nt) {
            int col = n0 + wn * 64 + nt * 16 + lo;
#pragma unroll
            for (int r = 0; r < 4; ++r) {
                float e = __expf(acc[mt][nt][r] * alpha - 2.f);
                e = fminf(e, 448.f);
                int pk = __builtin_amdgcn_cvt_pk_fp8_f32(e, e, 0, false);
                S[(size_t)(row + r) * Nn + col] = (unsigned char)(pk & 0xff);
                rsum[r] += __builtin_amdgcn_cvt_f32_fp8(pk, 0);
            }
        }
#pragma unroll
        for (int o = 1; o < 16; o <<= 1) {
#pragma unroll
            for (int r = 0; r < 4; ++r) rsum[r] += __shfl_xor(rsum[r], o);
        }
        if (lo == 0) {
#pragma unroll
            for (int r = 0; r < 4; ++r) atomicAdd(&lsum[row + r], rsum[r]);
        }
    }
}

// ---------------- PV: o_t[m,c] = (sum_j P[m,j] V[c,j]) / lsum[m], fp8 MFMA ----------------
__global__ __launch_bounds__(256, 3) void pv_fp8(
    const unsigned char* __restrict__ S, const unsigned char* __restrict__ V,
    const float* __restrict__ lsum, unsigned short* __restrict__ o_t) {
    __shared__ unsigned char lA[128 * 128];
    __shared__ unsigned char lB[128 * 128];
    int z = blockIdx.z;
    S += (size_t)z * SN;
    V += (size_t)z * NC;
    lsum += (size_t)z * Nn;
    o_t += (size_t)z * NC;
    int m0 = blockIdx.y * 128, n0 = blockIdx.x * 128;
    int t = threadIdx.x;
    int lane = t & 63, wave = t >> 6;
    int wm = wave >> 1, wn = wave & 1;
    int lo = lane & 15, quad = lane >> 4;

    f32x4 acc[4][4];
#pragma unroll
    for (int a1 = 0; a1 < 4; ++a1)
#pragma unroll
        for (int a2 = 0; a2 < 4; ++a2) acc[a1][a2] = (f32x4){0.f, 0.f, 0.f, 0.f};

    for (int k0 = 0; k0 < Nn; k0 += 128) {
#pragma unroll
        for (int p = 0; p < 4; ++p) {
            int ci = p * 256 + t;
            int row = ci >> 3, g = ci & 7;
            int gs = g ^ (row & 7);
            gll16(S + (size_t)(m0 + row) * Nn + k0 + gs * 16, &lA[ci * 16]);
        }
#pragma unroll
        for (int p = 0; p < 4; ++p) {
            int ci = p * 256 + t;
            int row = ci >> 3, g = ci & 7;
            int gs = g ^ (row & 7);
            gll16(V + (size_t)(n0 + row) * Nn + k0 + gs * 16, &lB[ci * 16]);
        }
        __syncthreads();
#pragma unroll
        for (int ks = 0; ks < 4; ++ks) {
            int g16 = ks * 2 + (quad >> 1);
            int h8 = (quad & 1) * 8;
            i64 aq[4], bq[4];
#pragma unroll
            for (int mt = 0; mt < 4; ++mt) {
                int R = wm * 64 + mt * 16 + lo;
                aq[mt] = *(const i64*)&lA[R * 128 + ((g16 ^ (R & 7)) * 16) + h8];
            }
#pragma unroll
            for (int nt = 0; nt < 4; ++nt) {
                int R = wn * 64 + nt * 16 + lo;
                bq[nt] = *(const i64*)&lB[R * 128 + ((g16 ^ (R & 7)) * 16) + h8];
            }
#pragma unroll
            for (int mt = 0; mt < 4; ++mt)
#pragma unroll
                for (int nt = 0; nt < 4; ++nt)
                    acc[mt][nt] = __builtin_amdgcn_mfma_f32_16x16x32_fp8_fp8(aq[mt], bq[nt], acc[mt][nt], 0, 0, 0);
        }
        __syncthreads();
    }

#pragma unroll
    for (int mt = 0; mt < 4; ++mt)
#pragma unroll
        for (int nt = 0; nt < 4; ++nt) {
            int row = m0 + wm * 64 + mt * 16 + quad * 4;
            int col = n0 + wn * 64 + nt * 16 + lo;
#pragma unroll
            for (int r = 0; r < 4; ++r) {
                float vv = acc[mt][nt][r] / lsum[row + r];
                o_t[(size_t)(row + r) * Cc + col] = f2bf(vv);
            }
        }
}

extern "C" void kernel_launch(void* const* d_in, const int* in_sizes, int n_in,
                              void* d_out, int out_size, void* d_ws, size_t ws_size,
                              hipStream_t stream) {
    const float* x     = (const float*)d_in[0];
    const float* gamma = (const float*)d_in[1];
    const float* beta  = (const float*)d_in[2];
    const float* wq = (const float*)d_in[3];
    const float* bq = (const float*)d_in[4];
    const float* wk = (const float*)d_in[5];
    const float* bk = (const float*)d_in[6];
    const float* wv = (const float*)d_in[7];
    const float* bv = (const float*)d_in[8];
    const float* wo = (const float*)d_in[9];
    const float* bo = (const float*)d_in[10];

    char* ws = (char*)d_ws;
    unsigned short* h_t  = (unsigned short*)(ws);                 // [B,N,C] bf16 16MB
    unsigned char*  q_8  = (unsigned char*)(ws + 16777216);       // [B,N,C] fp8 8.4MB
    unsigned char*  k_8  = (unsigned char*)(ws + 33554432);       // [B,N,C] fp8
    unsigned char*  v_8  = (unsigned char*)(ws + 50331648);       // [B,C,N] fp8
    unsigned short* o_t  = (unsigned short*)(ws + 67108864);      // [B,N,C] bf16
    unsigned char*  S    = (unsigned char*)(ws + 83886080);       // [B,N,N] fp8 67MB
    unsigned short* wqb  = (unsigned short*)(ws + 218103808);
    unsigned short* wkb  = (unsigned short*)(ws + 218628096);
    unsigned short* wvb  = (unsigned short*)(ws + 219152384);
    unsigned short* wob  = (unsigned short*)(ws + 219676672);
    float* statm         = (float*)(ws + 220200960);              // [128]
    float* statr         = (float*)(ws + 220201984);              // [128]
    float* lsum          = (float*)(ws + 220203008);              // [B*N] = 16384 floats

    const float SCALE = 0.044194173824159216f; // 512^-0.5

    cvt_kernel<<<256, 256, 0, stream>>>(wq, wqb, 65536);
    cvt_kernel<<<256, 256, 0, stream>>>(wk, wkb, 65536);
    cvt_kernel<<<256, 256, 0, stream>>>(wv, wvb, 65536);
    cvt_kernel<<<256, 256, 0, stream>>>(wo, wob, 65536);
    zero_kernel<<<16, 256, 0, stream>>>(lsum, 4096);

    gn_stats_kernel<<<128, 256, 0, stream>>>(x, statm, statr);
    gn_norm_kernel<<<dim3(64, 8, 4), 256, 0, stream>>>(x, statm, statr, gamma, beta, h_t);

    // q_8 = fp8(h . Wq^T + bq)   [B,N,C]  (scale folded into qk exp)
    gemm_bt<128, 0, 2, 3, 0><<<dim3(4, 32, 4), 256, 0, stream>>>(
        h_t, Cc, NC, wqb, Cc, 0, q_8, Cc, NC, bq, nullptr, 0, Cc, 1.f);
    // k_8 = fp8(h . Wk^T + bk)   [B,N,C]
    gemm_bt<128, 0, 2, 3, 0><<<dim3(4, 32, 4), 256, 0, stream>>>(
        h_t, Cc, NC, wkb, Cc, 0, k_8, Cc, NC, bk, nullptr, 0, Cc, 1.f);
    // v_8 = fp8(Wv . h^T + bv)   [B,C,N]
    gemm_bt<128, 0, 1, 3, 0><<<dim3(32, 4, 4), 256, 0, stream>>>(
        wvb, Cc, 0, h_t, Cc, NC, v_8, Nn, NC, bv, nullptr, 0, Cc, 1.f);

    // S = fp8(exp(q.k^T * scale - 2)); lsum = quantized row sums
    qk_fp8<<<dim3(32, 16, 4), 256, 0, stream>>>(q_8, k_8, S, lsum, SCALE);
    // o_t = (S . V^T) / lsum   bf16 [B,N,C]
    pv_fp8<<<dim3(4, 32, 4), 256, 0, stream>>>(S, v_8, lsum, o_t);

    // out = Wo . o^T + bo + x   fp32 [B,C,N]
    gemm_bt<128, 0, 1, 0, 1><<<dim3(32, 4, 4), 256, 0, stream>>>(
        wob, Cc, 0, o_t, Cc, NC, d_out, Nn, NC, bo, x, NC, Cc, 1.f);
}

// Round 7
// 314.387 us; speedup vs baseline: 2.5643x; 1.0338x over previous
//
#include <hip/hip_runtime.h>

using uint = unsigned int;
typedef short bf16x8 __attribute__((ext_vector_type(8)));
typedef _Float16 f16x8 __attribute__((ext_vector_type(8)));
typedef float f32x4 __attribute__((ext_vector_type(4)));
typedef long i64;
typedef i64 i64x2 __attribute__((ext_vector_type(2)));

static constexpr int Cc = 512;
static constexpr int Nn = 4096;               // H*W
static constexpr size_t NC = (size_t)Nn * Cc; // 2097152 elements
static constexpr size_t SN = (size_t)Nn * Nn; // 16777216 elements

__device__ __forceinline__ unsigned short f2bf(float f) {
    unsigned int u = __builtin_bit_cast(unsigned int, f);
    u = (u + 0x7fff + ((u >> 16) & 1)) >> 16;
    return (unsigned short)u;
}
__device__ __forceinline__ unsigned short f2h(float f) {
    _Float16 h = (_Float16)f;
    return __builtin_bit_cast(unsigned short, h);
}
// k-permutation within 64-byte chunks so fp8 MFMA fragments are b128-contiguous:
// pos[5:4]=k[4:3] (quad), pos[3]=k[5] (ks), pos[2:0]=k[2:0]
__device__ __forceinline__ int perm64(int k) {
    return (k & ~63) | ((k & 0x18) << 1) | ((k & 0x20) >> 2) | (k & 7);
}

__device__ __forceinline__ void gll16(const void* g, void* l) {
    __builtin_amdgcn_global_load_lds(
        (const __attribute__((address_space(1))) void*)g,
        (__attribute__((address_space(3))) void*)l, 16, 0, 0);
}

// ---------------- fp32 -> bf16 weight convert ----------------
__global__ void cvt_kernel(const float* __restrict__ in, unsigned short* __restrict__ out, int n4) {
    int i = blockIdx.x * blockDim.x + threadIdx.x;
    if (i < n4) {
        float4 v = ((const float4*)in)[i];
        out[i * 4 + 0] = f2bf(v.x);
        out[i * 4 + 1] = f2bf(v.y);
        out[i * 4 + 2] = f2bf(v.z);
        out[i * 4 + 3] = f2bf(v.w);
    }
}

// ---------------- zero the row-sum accumulator ----------------
__global__ void zero_kernel(float* __restrict__ p, int n4) {
    int i = blockIdx.x * blockDim.x + threadIdx.x;
    if (i < n4) ((float4*)p)[i] = make_float4(0.f, 0.f, 0.f, 0.f);
}

// ---------------- GN pass 1: stats per (b,g) ----------------
__global__ void gn_stats_kernel(const float* __restrict__ x, float* __restrict__ meanb,
                                float* __restrict__ rsb) {
    int bg = blockIdx.x; // 128 = B*32
    const float* slab = x + (size_t)bg * 16 * Nn;
    const float4* s4 = (const float4*)slab;
    int t = threadIdx.x; // 256
    float s1 = 0.f, s2 = 0.f;
#pragma unroll 8
    for (int k = 0; k < 64; ++k) {
        float4 v = s4[k * 256 + t];
        s1 += v.x + v.y + v.z + v.w;
        s2 += v.x * v.x + v.y * v.y + v.z * v.z + v.w * v.w;
    }
#pragma unroll
    for (int o = 32; o > 0; o >>= 1) { s1 += __shfl_down(s1, o); s2 += __shfl_down(s2, o); }
    __shared__ float r1[4], r2[4];
    int wv_ = t >> 6, ln = t & 63;
    if (ln == 0) { r1[wv_] = s1; r2[wv_] = s2; }
    __syncthreads();
    if (t == 0) {
        float a1 = r1[0] + r1[1] + r1[2] + r1[3];
        float a2 = r2[0] + r2[1] + r2[2] + r2[3];
        float mean = a1 * (1.f / 65536.f);
        float var = a2 * (1.f / 65536.f) - mean * mean;
        meanb[bg] = mean;
        rsb[bg] = rsqrtf(var + 1e-6f);
    }
}

// ---------------- GN pass 2: normalize + transpose via LDS tile ----------------
__global__ __launch_bounds__(256) void gn_norm_kernel(
    const float* __restrict__ x, const float* __restrict__ meanb, const float* __restrict__ rsb,
    const float* __restrict__ gamma, const float* __restrict__ beta,
    unsigned short* __restrict__ h_t) {
    __shared__ float tile[64][65];
    int n0 = blockIdx.x * 64, c0 = blockIdx.y * 64, b = blockIdx.z;
    int t = threadIdx.x;
    const float* xb = x + (size_t)b * Cc * Nn;
#pragma unroll
    for (int j = 0; j < 4; ++j) {
        int i = j * 256 + t;
        int c = i >> 4;       // 0..63
        int n4 = i & 15;      // float4 index within row
        int cg = c0 + c;
        float4 v = ((const float4*)(xb + (size_t)cg * Nn + n0))[n4];
        int g = cg >> 4;
        float mean = meanb[b * 32 + g], rs = rsb[b * 32 + g];
        float ga = gamma[cg] * rs;
        float be = beta[cg] - mean * ga;
        tile[n4 * 4 + 0][c] = v.x * ga + be;
        tile[n4 * 4 + 1][c] = v.y * ga + be;
        tile[n4 * 4 + 2][c] = v.z * ga + be;
        tile[n4 * 4 + 3][c] = v.w * ga + be;
    }
    __syncthreads();
    int n = t >> 2;                 // 0..63
    int cpart = (t & 3) * 16;       // 0,16,32,48
    unsigned short o[16];
#pragma unroll
    for (int q = 0; q < 16; ++q) o[q] = f2bf(tile[n][cpart + q]);
    unsigned short* dst = h_t + (size_t)b * NC + (size_t)(n0 + n) * Cc + c0 + cpart;
    ((uint4*)dst)[0] = ((uint4*)o)[0];
    ((uint4*)dst)[1] = ((uint4*)o)[1];
}

// ---------------- bf16 GEMM: out[M,N] = (A[M,K] * Bt[N,K]^T + bias) * alpha (+res) --------
// Block tile BM x 128, 4 waves as 2x2, wave tile (BM/2) x 64. BK=64.
// DT: 0 bf16, 1 fp16. BIAS_MODE: 0 none, 1 bias[m], 2 bias[n].
// OUT_MODE: 0 fp32, 1 bf16, 2 fp16, 3 fp8(e4m3) with perm64 column layout.
template <int BM, int DT, int BIAS_MODE, int OUT_MODE, int HAS_RES>
__global__ __launch_bounds__(256, 2) void gemm_bt(
    const unsigned short* __restrict__ A, int lda, size_t sA,
    const unsigned short* __restrict__ Bt, int ldb, size_t sB,
    void* __restrict__ outp, int ldc, size_t sC,
    const float* __restrict__ bias,
    const float* __restrict__ res, size_t sR,
    int K, float alpha) {
    constexpr int MT = BM / 32;  // m-fragments per wave (4 or 8)
    __shared__ unsigned short lA[BM * 64];
    __shared__ unsigned short lB[128 * 64];
    int z = blockIdx.z;
    A += (size_t)z * sA;
    Bt += (size_t)z * sB;
    int m0 = blockIdx.y * BM, n0 = blockIdx.x * 128;
    int t = threadIdx.x;
    int lane = t & 63, wave = t >> 6;
    int wm = wave >> 1, wn = wave & 1;
    int lo = lane & 15, quad = lane >> 4;

    f32x4 acc[MT][4];
#pragma unroll
    for (int a1 = 0; a1 < MT; ++a1)
#pragma unroll
        for (int a2 = 0; a2 < 4; ++a2) acc[a1][a2] = (f32x4){0.f, 0.f, 0.f, 0.f};

    for (int k0 = 0; k0 < K; k0 += 64) {
#pragma unroll
        for (int p = 0; p < MT; ++p) {
            int ci = p * 256 + t;
            int row = ci >> 3;
            int gs = (ci ^ row) & 7;  // swizzled granule
            gll16(A + (size_t)(m0 + row) * lda + k0 + gs * 8, &lA[(size_t)ci * 8]);
        }
#pragma unroll
        for (int p = 0; p < 4; ++p) {
            int ci = p * 256 + t;
            int row = ci >> 3;
            int gs = (ci ^ row) & 7;
            gll16(Bt + (size_t)(n0 + row) * ldb + k0 + gs * 8, &lB[(size_t)ci * 8]);
        }
        __syncthreads();
#pragma unroll
        for (int ks = 0; ks < 2; ++ks) {
            int G = quad + ks * 4;  // granule index (8 halfs each)
            bf16x8 af[MT], bfr[4];
#pragma unroll
            for (int mt = 0; mt < MT; ++mt) {
                int R = wm * (BM / 2) + mt * 16 + lo;
                af[mt] = *(const bf16x8*)&lA[R * 64 + (((G ^ R) & 7) << 3)];
            }
#pragma unroll
            for (int nt = 0; nt < 4; ++nt) {
                int R = wn * 64 + nt * 16 + lo;
                bfr[nt] = *(const bf16x8*)&lB[R * 64 + (((G ^ R) & 7) << 3)];
            }
#pragma unroll
            for (int mt = 0; mt < MT; ++mt)
#pragma unroll
                for (int nt = 0; nt < 4; ++nt) {
                    if (DT == 0)
                        acc[mt][nt] = __builtin_amdgcn_mfma_f32_16x16x32_bf16(af[mt], bfr[nt], acc[mt][nt], 0, 0, 0);
                    else
                        acc[mt][nt] = __builtin_amdgcn_mfma_f32_16x16x32_f16(
                            __builtin_bit_cast(f16x8, af[mt]), __builtin_bit_cast(f16x8, bfr[nt]),
                            acc[mt][nt], 0, 0, 0);
                }
        }
        __syncthreads();
    }

    size_t zc = (size_t)z * sC;
    float* outf = (float*)outp + zc;
    unsigned short* outb = (unsigned short*)outp + zc;
    unsigned char* outc = (unsigned char*)outp + zc;
    const float* resz = HAS_RES ? res + (size_t)z * sR : nullptr;

#pragma unroll
    for (int mt = 0; mt < MT; ++mt) {
#pragma unroll
        for (int nt = 0; nt < 4; ++nt) {
            int row = m0 + wm * (BM / 2) + mt * 16 + quad * 4;
            int col = n0 + wn * 64 + nt * 16 + lo;
            float bn = (BIAS_MODE == 2) ? bias[col] : 0.f;
#pragma unroll
            for (int r = 0; r < 4; ++r) {
                float vv = acc[mt][nt][r];
                if (BIAS_MODE == 1) vv += bias[row + r];
                if (BIAS_MODE == 2) vv += bn;
                vv *= alpha;
                if (OUT_MODE == 3) {
                    float e = fmaxf(fminf(vv, 448.f), -448.f);
                    int pk = __builtin_amdgcn_cvt_pk_fp8_f32(e, e, 0, false);
                    outc[(size_t)(row + r) * ldc + perm64(col)] = (unsigned char)(pk & 0xff);
                } else {
                    size_t off = (size_t)(row + r) * ldc + col;
                    if (HAS_RES) vv += resz[off];
                    if (OUT_MODE == 0) outf[off] = vv;
                    else if (OUT_MODE == 1) outb[off] = f2bf(vv);
                    else outb[off] = f2h(vv);
                }
            }
        }
    }
}

// ---------------- QK: S = fp8(exp((Q.K^T)*alpha - 2)), lsum += quantized row sums ----
// Q,K fp8 [B,N,C] in perm64 k-layout. Block tile 256x128, waves 2x2, BK=128.
// Frag reads are ds_read_b128 in the m97-proven conflict-free swizzle shape.
__global__ __launch_bounds__(256, 2) void qk_fp8(
    const unsigned char* __restrict__ Q, const unsigned char* __restrict__ Kt,
    unsigned char* __restrict__ S, float* __restrict__ lsum, float alpha) {
    __shared__ unsigned char lA[256 * 128]; // 32 KB
    __shared__ unsigned char lB[128 * 128]; // 16 KB
    int z = blockIdx.z;
    Q += (size_t)z * NC;
    Kt += (size_t)z * NC;
    S += (size_t)z * SN;
    lsum += (size_t)z * Nn;
    int m0 = blockIdx.y * 256, n0 = blockIdx.x * 128;
    int t = threadIdx.x;
    int lane = t & 63, wave = t >> 6;
    int wm = wave >> 1, wn = wave & 1;
    int lo = lane & 15, quad = lane >> 4;

    f32x4 acc[8][4];
#pragma unroll
    for (int a1 = 0; a1 < 8; ++a1)
#pragma unroll
        for (int a2 = 0; a2 < 4; ++a2) acc[a1][a2] = (f32x4){0.f, 0.f, 0.f, 0.f};

    for (int k0 = 0; k0 < Cc; k0 += 128) {
#pragma unroll
        for (int p = 0; p < 8; ++p) {
            int ci = p * 256 + t;
            int row = ci >> 3, g = ci & 7;
            int gs = g ^ (row & 7);
            gll16(Q + (size_t)(m0 + row) * Cc + k0 + gs * 16, &lA[ci * 16]);
        }
#pragma unroll
        for (int p = 0; p < 4; ++p) {
            int ci = p * 256 + t;
            int row = ci >> 3, g = ci & 7;
            int gs = g ^ (row & 7);
            gll16(Kt + (size_t)(n0 + row) * Cc + k0 + gs * 16, &lB[ci * 16]);
        }
        __syncthreads();
#pragma unroll
        for (int c = 0; c < 2; ++c) {
            int gb = c * 4 + quad;  // 16B granule this quad consumes (both ks halves)
            i64x2 aq[8], bq[4];
#pragma unroll
            for (int mt = 0; mt < 8; ++mt) {
                int R = wm * 128 + mt * 16 + lo;
                aq[mt] = *(const i64x2*)&lA[R * 128 + ((gb ^ (R & 7)) << 4)];
            }
#pragma unroll
            for (int nt = 0; nt < 4; ++nt) {
                int R = wn * 64 + nt * 16 + lo;
                bq[nt] = *(const i64x2*)&lB[R * 128 + ((gb ^ (R & 7)) << 4)];
            }
#pragma unroll
            for (int ks = 0; ks < 2; ++ks)
#pragma unroll
                for (int mt = 0; mt < 8; ++mt)
#pragma unroll
                    for (int nt = 0; nt < 4; ++nt)
                        acc[mt][nt] = __builtin_amdgcn_mfma_f32_16x16x32_fp8_fp8(
                            aq[mt][ks], bq[nt][ks], acc[mt][nt], 0, 0, 0);
        }
        __syncthreads();
    }

#pragma unroll
    for (int mt = 0; mt < 8; ++mt) {
        int row = m0 + wm * 128 + mt * 16 + quad * 4;
        float rsum[4] = {0.f, 0.f, 0.f, 0.f};
#pragma unroll
        for (int nt = 0; nt < 4; ++nt) {
            int col = n0 + wn * 64 + nt * 16 + lo;
            int colp = perm64(col);
#pragma unroll
            for (int r = 0; r < 4; ++r) {
                float e = __expf(acc[mt][nt][r] * alpha - 2.f);
                e = fminf(e, 448.f);
                int pk = __builtin_amdgcn_cvt_pk_fp8_f32(e, e, 0, false);
                S[(size_t)(row + r) * Nn + colp] = (unsigned char)(pk & 0xff);
                rsum[r] += __builtin_amdgcn_cvt_f32_fp8(pk, 0);
            }
        }
#pragma unroll
        for (int o = 1; o < 16; o <<= 1) {
#pragma unroll
            for (int r = 0; r < 4; ++r) rsum[r] += __shfl_xor(rsum[r], o);
        }
        if (lo == 0) {
#pragma unroll
            for (int r = 0; r < 4; ++r) atomicAdd(&lsum[row + r], rsum[r]);
        }
    }
}

// ---------------- PV: o_t[m,c] = (sum_j P[m,j] V[c,j]) / lsum[m], fp8 MFMA ----------------
// S [B,N,N] and V [B,C,N] both in perm64 j-layout. b128 frag reads.
__global__ __launch_bounds__(256, 3) void pv_fp8(
    const unsigned char* __restrict__ S, const unsigned char* __restrict__ V,
    const float* __restrict__ lsum, unsigned short* __restrict__ o_t) {
    __shared__ unsigned char lA[128 * 128];
    __shared__ unsigned char lB[128 * 128];
    int z = blockIdx.z;
    S += (size_t)z * SN;
    V += (size_t)z * NC;
    lsum += (size_t)z * Nn;
    o_t += (size_t)z * NC;
    int m0 = blockIdx.y * 128, n0 = blockIdx.x * 128;
    int t = threadIdx.x;
    int lane = t & 63, wave = t >> 6;
    int wm = wave >> 1, wn = wave & 1;
    int lo = lane & 15, quad = lane >> 4;

    f32x4 acc[4][4];
#pragma unroll
    for (int a1 = 0; a1 < 4; ++a1)
#pragma unroll
        for (int a2 = 0; a2 < 4; ++a2) acc[a1][a2] = (f32x4){0.f, 0.f, 0.f, 0.f};

    for (int k0 = 0; k0 < Nn; k0 += 128) {
#pragma unroll
        for (int p = 0; p < 4; ++p) {
            int ci = p * 256 + t;
            int row = ci >> 3, g = ci & 7;
            int gs = g ^ (row & 7);
            gll16(S + (size_t)(m0 + row) * Nn + k0 + gs * 16, &lA[ci * 16]);
        }
#pragma unroll
        for (int p = 0; p < 4; ++p) {
            int ci = p * 256 + t;
            int row = ci >> 3, g = ci & 7;
            int gs = g ^ (row & 7);
            gll16(V + (size_t)(n0 + row) * Nn + k0 + gs * 16, &lB[ci * 16]);
        }
        __syncthreads();
#pragma unroll
        for (int c = 0; c < 2; ++c) {
            int gb = c * 4 + quad;
            i64x2 aq[4], bq[4];
#pragma unroll
            for (int mt = 0; mt < 4; ++mt) {
                int R = wm * 64 + mt * 16 + lo;
                aq[mt] = *(const i64x2*)&lA[R * 128 + ((gb ^ (R & 7)) << 4)];
            }
#pragma unroll
            for (int nt = 0; nt < 4; ++nt) {
                int R = wn * 64 + nt * 16 + lo;
                bq[nt] = *(const i64x2*)&lB[R * 128 + ((gb ^ (R & 7)) << 4)];
            }
#pragma unroll
            for (int ks = 0; ks < 2; ++ks)
#pragma unroll
                for (int mt = 0; mt < 4; ++mt)
#pragma unroll
                    for (int nt = 0; nt < 4; ++nt)
                        acc[mt][nt] = __builtin_amdgcn_mfma_f32_16x16x32_fp8_fp8(
                            aq[mt][ks], bq[nt][ks], acc[mt][nt], 0, 0, 0);
        }
        __syncthreads();
    }

#pragma unroll
    for (int mt = 0; mt < 4; ++mt)
#pragma unroll
        for (int nt = 0; nt < 4; ++nt) {
            int row = m0 + wm * 64 + mt * 16 + quad * 4;
            int col = n0 + wn * 64 + nt * 16 + lo;
#pragma unroll
            for (int r = 0; r < 4; ++r) {
                float vv = acc[mt][nt][r] / lsum[row + r];
                o_t[(size_t)(row + r) * Cc + col] = f2bf(vv);
            }
        }
}

extern "C" void kernel_launch(void* const* d_in, const int* in_sizes, int n_in,
                              void* d_out, int out_size, void* d_ws, size_t ws_size,
                              hipStream_t stream) {
    const float* x     = (const float*)d_in[0];
    const float* gamma = (const float*)d_in[1];
    const float* beta  = (const float*)d_in[2];
    const float* wq = (const float*)d_in[3];
    const float* bq = (const float*)d_in[4];
    const float* wk = (const float*)d_in[5];
    const float* bk = (const float*)d_in[6];
    const float* wv = (const float*)d_in[7];
    const float* bv = (const float*)d_in[8];
    const float* wo = (const float*)d_in[9];
    const float* bo = (const float*)d_in[10];

    char* ws = (char*)d_ws;
    unsigned short* h_t  = (unsigned short*)(ws);                 // [B,N,C] bf16 16MB
    unsigned char*  q_8  = (unsigned char*)(ws + 16777216);       // [B,N,C] fp8 perm64
    unsigned char*  k_8  = (unsigned char*)(ws + 33554432);       // [B,N,C] fp8 perm64
    unsigned char*  v_8  = (unsigned char*)(ws + 50331648);       // [B,C,N] fp8 perm64
    unsigned short* o_t  = (unsigned short*)(ws + 67108864);      // [B,N,C] bf16
    unsigned char*  S    = (unsigned char*)(ws + 83886080);       // [B,N,N] fp8 perm64 67MB
    unsigned short* wqb  = (unsigned short*)(ws + 218103808);
    unsigned short* wkb  = (unsigned short*)(ws + 218628096);
    unsigned short* wvb  = (unsigned short*)(ws + 219152384);
    unsigned short* wob  = (unsigned short*)(ws + 219676672);
    float* statm         = (float*)(ws + 220200960);              // [128]
    float* statr         = (float*)(ws + 220201984);              // [128]
    float* lsum          = (float*)(ws + 220203008);              // [B*N] = 16384 floats

    const float SCALE = 0.044194173824159216f; // 512^-0.5

    cvt_kernel<<<256, 256, 0, stream>>>(wq, wqb, 65536);
    cvt_kernel<<<256, 256, 0, stream>>>(wk, wkb, 65536);
    cvt_kernel<<<256, 256, 0, stream>>>(wv, wvb, 65536);
    cvt_kernel<<<256, 256, 0, stream>>>(wo, wob, 65536);
    zero_kernel<<<16, 256, 0, stream>>>(lsum, 4096);

    gn_stats_kernel<<<128, 256, 0, stream>>>(x, statm, statr);
    gn_norm_kernel<<<dim3(64, 8, 4), 256, 0, stream>>>(x, statm, statr, gamma, beta, h_t);

    // q_8 = fp8(h . Wq^T + bq)   [B,N,C] perm64  (scale folded into qk exp)
    gemm_bt<128, 0, 2, 3, 0><<<dim3(4, 32, 4), 256, 0, stream>>>(
        h_t, Cc, NC, wqb, Cc, 0, q_8, Cc, NC, bq, nullptr, 0, Cc, 1.f);
    // k_8 = fp8(h . Wk^T + bk)   [B,N,C] perm64
    gemm_bt<128, 0, 2, 3, 0><<<dim3(4, 32, 4), 256, 0, stream>>>(
        h_t, Cc, NC, wkb, Cc, 0, k_8, Cc, NC, bk, nullptr, 0, Cc, 1.f);
    // v_8 = fp8(Wv . h^T + bv)   [B,C,N] perm64
    gemm_bt<128, 0, 1, 3, 0><<<dim3(32, 4, 4), 256, 0, stream>>>(
        wvb, Cc, 0, h_t, Cc, NC, v_8, Nn, NC, bv, nullptr, 0, Cc, 1.f);

    // S = fp8(exp(q.k^T * scale - 2)); lsum = quantized row sums
    qk_fp8<<<dim3(32, 16, 4), 256, 0, stream>>>(q_8, k_8, S, lsum, SCALE);
    // o_t = (S . V^T) / lsum   bf16 [B,N,C]
    pv_fp8<<<dim3(4, 32, 4), 256, 0, stream>>>(S, v_8, lsum, o_t);

    // out = Wo . o^T + bo + x   fp32 [B,C,N]
    gemm_bt<128, 0, 1, 0, 1><<<dim3(32, 4, 4), 256, 0, stream>>>(
        wob, Cc, 0, o_t, Cc, NC, d_out, Nn, NC, bo, x, NC, Cc, 1.f);
}